// Round 1
// baseline (719.752 us; speedup 1.0000x reference)
//
#include <hip/hip_runtime.h>
#include <math.h>

#define Fdim 128
#define U0 64
#define H0c 8
#define U1 40

__device__ __forceinline__ void atomicMaxFloat(float* addr, float value) {
    // Works for all finite floats when slot initialized to -inf:
    // non-negative floats order as signed ints; negative floats reverse-order as unsigned.
    if (value >= 0.0f) {
        atomicMax((int*)addr, __float_as_int(value));
    } else {
        atomicMin((unsigned int*)addr, (unsigned int)__float_as_int(value));
    }
}

__global__ void k_init(float* m0, float* d0, float* hbuf, float* m1, float* d1,
                       float* out, int n) {
    int stride = gridDim.x * blockDim.x;
    int t = blockIdx.x * blockDim.x + threadIdx.x;
    for (int i = t; i < n * 8; i += stride) { m0[i] = -INFINITY; d0[i] = 0.f; }
    for (int i = t; i < n * 64; i += stride) hbuf[i] = 0.f;
    for (int i = t; i < n; i += stride) { m1[i] = -INFINITY; d1[i] = 0.f; }
    for (int i = t; i < n * 40; i += stride) out[i] = 0.f;
}

// Layer 0 node transforms: Q0 = relu(x@wq0+bq0), K0 = relu(x@wk0+bk0), V0 = x@wv0
// One block per node; 192 threads = 3 waves (Q cols / K cols / V cols).
__global__ __launch_bounds__(192) void k_node0(
    const float* __restrict__ x,
    const float* __restrict__ wq, const float* __restrict__ bq,
    const float* __restrict__ wk, const float* __restrict__ bk,
    const float* __restrict__ wv,
    float* __restrict__ Q0, float* __restrict__ K0, float* __restrict__ V0) {
    __shared__ float xs[Fdim];
    int node = blockIdx.x;
    int t = threadIdx.x;
    if (t < Fdim) xs[t] = x[(size_t)node * Fdim + t];
    __syncthreads();
    int which = t >> 6;   // 0=Q, 1=K, 2=V
    int colv = t & 63;
    const float* W = (which == 0) ? wq : ((which == 1) ? wk : wv);
    float acc = 0.f;
    #pragma unroll 4
    for (int k = 0; k < Fdim; k += 4) {
        float4 xv = *(const float4*)&xs[k];
        acc += xv.x * W[(k + 0) * 64 + colv];
        acc += xv.y * W[(k + 1) * 64 + colv];
        acc += xv.z * W[(k + 2) * 64 + colv];
        acc += xv.w * W[(k + 3) * 64 + colv];
    }
    size_t o = (size_t)node * 64 + colv;
    if (which == 0)       Q0[o] = fmaxf(acc + bq[colv], 0.f);
    else if (which == 1)  K0[o] = fmaxf(acc + bk[colv], 0.f);
    else                  V0[o] = acc;
}

// att0[e,h] = dot(Q0[row,h,:8], K0[col,h,:8]) / sqrt(8); segment max into m0[row,h]
__global__ void k_att0(const int* __restrict__ row, const int* __restrict__ col,
                       const float* __restrict__ Q0, const float* __restrict__ K0,
                       float* __restrict__ att0, float* __restrict__ m0,
                       int E_, int Etot) {
    int t = blockIdx.x * blockDim.x + threadIdx.x;
    if (t >= Etot * 8) return;
    int e = t >> 3, h = t & 7;
    int r, c;
    if (e < E_) { r = row[e]; c = col[e]; } else { r = e - E_; c = r; }
    const float4* q = (const float4*)&Q0[(size_t)r * 64 + h * 8];
    const float4* k = (const float4*)&K0[(size_t)c * 64 + h * 8];
    float4 q0 = q[0], q1 = q[1], k0 = k[0], k1 = k[1];
    float att = q0.x * k0.x + q0.y * k0.y + q0.z * k0.z + q0.w * k0.w
              + q1.x * k1.x + q1.y * k1.y + q1.z * k1.z + q1.w * k1.w;
    att *= 0.35355339059327373f;  // 1/sqrt(8)
    att0[t] = att;
    atomicMaxFloat(&m0[r * 8 + h], att);
}

__global__ void k_exp0(const int* __restrict__ row, const float* __restrict__ m0,
                       float* __restrict__ att0, float* __restrict__ d0,
                       int E_, int Etot) {
    int t = blockIdx.x * blockDim.x + threadIdx.x;
    if (t >= Etot * 8) return;
    int e = t >> 3, h = t & 7;
    int r = (e < E_) ? row[e] : (e - E_);
    float ex = __expf(att0[t] - m0[r * 8 + h]);
    att0[t] = ex;
    atomicAdd(&d0[r * 8 + h], ex);
}

// One wave per edge: lane j accumulates V0[col, j] * alpha[e, j/8] into hbuf[row, j]
__global__ void k_agg0(const int* __restrict__ row, const int* __restrict__ col,
                       const float* __restrict__ V0, const float* __restrict__ att0,
                       const float* __restrict__ d0, float* __restrict__ hbuf,
                       int E_, int Etot) {
    int gid = blockIdx.x * blockDim.x + threadIdx.x;
    int e = gid >> 6;
    int j = gid & 63;
    if (e >= Etot) return;
    int r, c;
    if (e < E_) { r = row[e]; c = col[e]; } else { r = e - E_; c = r; }
    int h = j >> 3;
    float alpha = att0[(size_t)e * 8 + h] / d0[r * 8 + h];
    atomicAdd(&hbuf[(size_t)r * 64 + j], V0[(size_t)c * 64 + j] * alpha);
}

// Finalize h = relu(hbuf + b0), then Q1 = relu(h@wq1+bq1), K1 = relu(h@wk1+bk1), V1 = h@wv1
__global__ __launch_bounds__(64) void k_node1(
    const float* __restrict__ hbuf, const float* __restrict__ b0,
    const float* __restrict__ wq1, const float* __restrict__ bq1,
    const float* __restrict__ wk1, const float* __restrict__ bk1,
    const float* __restrict__ wv1,
    float* __restrict__ Q1, float* __restrict__ K1, float* __restrict__ V1) {
    __shared__ float hs[U0];
    int node = blockIdx.x;
    int t = threadIdx.x;
    hs[t] = fmaxf(hbuf[(size_t)node * 64 + t] + b0[t], 0.f);
    __syncthreads();
    if (t < 40) {
        float acc = 0.f;
        #pragma unroll 8
        for (int k = 0; k < 64; k++) acc += hs[k] * wv1[k * 40 + t];
        V1[(size_t)node * 40 + t] = acc;
    } else if (t == 40) {
        float acc = 0.f;
        for (int k = 0; k < 64; k++) acc += hs[k] * wq1[k];
        Q1[node] = fmaxf(acc + bq1[0], 0.f);
    } else if (t == 41) {
        float acc = 0.f;
        for (int k = 0; k < 64; k++) acc += hs[k] * wk1[k];
        K1[node] = fmaxf(acc + bk1[0], 0.f);
    }
}

__global__ void k_att1(const int* __restrict__ row, const int* __restrict__ col,
                       const float* __restrict__ Q1, const float* __restrict__ K1,
                       float* __restrict__ att1, float* __restrict__ m1,
                       int E_, int Etot) {
    int e = blockIdx.x * blockDim.x + threadIdx.x;
    if (e >= Etot) return;
    int r, c;
    if (e < E_) { r = row[e]; c = col[e]; } else { r = e - E_; c = r; }
    float att = Q1[r] * K1[c];  // a_units = 1 -> scale 1
    att1[e] = att;
    atomicMaxFloat(&m1[r], att);
}

__global__ void k_exp1(const int* __restrict__ row, const float* __restrict__ m1,
                       float* __restrict__ att1, float* __restrict__ d1,
                       int E_, int Etot) {
    int e = blockIdx.x * blockDim.x + threadIdx.x;
    if (e >= Etot) return;
    int r = (e < E_) ? row[e] : (e - E_);
    float ex = __expf(att1[e] - m1[r]);
    att1[e] = ex;
    atomicAdd(&d1[r], ex);
}

// One wave per edge, lanes 0..39 active
__global__ void k_agg1(const int* __restrict__ row, const int* __restrict__ col,
                       const float* __restrict__ V1, const float* __restrict__ att1,
                       const float* __restrict__ d1, float* __restrict__ out,
                       int E_, int Etot) {
    int gid = blockIdx.x * blockDim.x + threadIdx.x;
    int e = gid >> 6;
    int j = gid & 63;
    if (e >= Etot || j >= 40) return;
    int r, c;
    if (e < E_) { r = row[e]; c = col[e]; } else { r = e - E_; c = r; }
    float alpha = att1[e] / d1[r];
    atomicAdd(&out[(size_t)r * 40 + j], V1[(size_t)c * 40 + j] * alpha);
}

__global__ void k_bias(float* __restrict__ out, const float* __restrict__ b1, int n) {
    int t = blockIdx.x * blockDim.x + threadIdx.x;
    if (t < n * 40) out[t] += b1[t % 40];
}

extern "C" void kernel_launch(void* const* d_in, const int* in_sizes, int n_in,
                              void* d_out, int out_size, void* d_ws, size_t ws_size,
                              hipStream_t stream) {
    const float* x   = (const float*)d_in[0];
    const int*   ei  = (const int*)d_in[1];
    const float* wq0 = (const float*)d_in[2];
    const float* bq0 = (const float*)d_in[3];
    const float* wk0 = (const float*)d_in[4];
    const float* bk0 = (const float*)d_in[5];
    const float* wv0 = (const float*)d_in[6];
    const float* b0  = (const float*)d_in[7];
    const float* wq1 = (const float*)d_in[8];
    const float* bq1 = (const float*)d_in[9];
    const float* wk1 = (const float*)d_in[10];
    const float* bk1 = (const float*)d_in[11];
    const float* wv1 = (const float*)d_in[12];
    const float* b1  = (const float*)d_in[13];

    int n    = in_sizes[0] / Fdim;   // 50000
    int E_   = in_sizes[1] / 2;      // 800000
    int Etot = E_ + n;               // self-loops appended
    const int* row = ei;
    const int* col = ei + E_;

    float* ws  = (float*)d_ws;
    float* Q0   = ws; ws += (size_t)n * 64;
    float* K0   = ws; ws += (size_t)n * 64;
    float* V0   = ws; ws += (size_t)n * 64;
    float* hbuf = ws; ws += (size_t)n * 64;
    float* m0   = ws; ws += (size_t)n * 8;
    float* d0   = ws; ws += (size_t)n * 8;
    float* att0 = ws; ws += (size_t)Etot * 8;
    float* Q1   = ws; ws += n;
    float* K1   = ws; ws += n;
    float* V1   = ws; ws += (size_t)n * 40;
    float* m1   = ws; ws += n;
    float* d1   = ws; ws += n;
    float* att1 = ws; ws += Etot;
    float* out  = (float*)d_out;

    k_init<<<2048, 256, 0, stream>>>(m0, d0, hbuf, m1, d1, out, n);
    k_node0<<<n, 192, 0, stream>>>(x, wq0, bq0, wk0, bk0, wv0, Q0, K0, V0);

    int t8 = Etot * 8;
    k_att0<<<(t8 + 255) / 256, 256, 0, stream>>>(row, col, Q0, K0, att0, m0, E_, Etot);
    k_exp0<<<(t8 + 255) / 256, 256, 0, stream>>>(row, m0, att0, d0, E_, Etot);

    long long t64 = (long long)Etot * 64;
    k_agg0<<<(int)((t64 + 255) / 256), 256, 0, stream>>>(row, col, V0, att0, d0, hbuf, E_, Etot);

    k_node1<<<n, 64, 0, stream>>>(hbuf, b0, wq1, bq1, wk1, bk1, wv1, Q1, K1, V1);

    k_att1<<<(Etot + 255) / 256, 256, 0, stream>>>(row, col, Q1, K1, att1, m1, E_, Etot);
    k_exp1<<<(Etot + 255) / 256, 256, 0, stream>>>(row, m1, att1, d1, E_, Etot);
    k_agg1<<<(int)((t64 + 255) / 256), 256, 0, stream>>>(row, col, V1, att1, d1, out, E_, Etot);

    k_bias<<<(n * 40 + 255) / 256, 256, 0, stream>>>(out, b1, n);
}

// Round 2
// 558.690 us; speedup vs baseline: 1.2883x; 1.2883x over previous
//
#include <hip/hip_runtime.h>
#include <math.h>

#define Fdim 128

// ---------------- CSR build ----------------

__global__ void k_zero(int* deg, int n) {
    int t = blockIdx.x * blockDim.x + threadIdx.x;
    if (t < n) deg[t] = 0;
}

__global__ void k_hist(const int* __restrict__ row, int* __restrict__ deg,
                       int E_, int Etot) {
    int t = blockIdx.x * blockDim.x + threadIdx.x;
    if (t >= Etot) return;
    int r = (t < E_) ? row[t] : (t - E_);
    atomicAdd(&deg[r], 1);
}

// Exclusive scan of cnt[0..n) -> rowptr[0..n], and cursor copy back into cnt.
__global__ __launch_bounds__(1024) void k_scan(int* __restrict__ cnt,
                                               int* __restrict__ rowptr, int n) {
    __shared__ int wsum[16];
    __shared__ int carry_s;
    int lane = threadIdx.x & 63, wid = threadIdx.x >> 6;
    if (threadIdx.x == 0) carry_s = 0;
    __syncthreads();
    for (int base = 0; base < n; base += 1024) {
        int i = base + threadIdx.x;
        int v = (i < n) ? cnt[i] : 0;
        int incl = v;
        #pragma unroll
        for (int off = 1; off < 64; off <<= 1) {
            int t = __shfl_up(incl, off);
            if (lane >= off) incl += t;
        }
        if (lane == 63) wsum[wid] = incl;
        __syncthreads();
        if (wid == 0 && lane < 16) {
            int w = wsum[lane];
            int wi = w;
            #pragma unroll
            for (int off = 1; off < 16; off <<= 1) {
                int t = __shfl_up(wi, off);
                if (lane >= off) wi += t;
            }
            wsum[lane] = wi - w;  // exclusive wave offset
        }
        __syncthreads();
        int excl = incl - v + wsum[wid] + carry_s;
        if (i < n) { rowptr[i] = excl; cnt[i] = excl; }
        __syncthreads();
        if (threadIdx.x == 1023) carry_s += wsum[15] + incl;
        __syncthreads();
    }
    if (threadIdx.x == 0) rowptr[n] = carry_s;
}

// ---------------- Layer 0 node transforms ----------------
__global__ __launch_bounds__(192) void k_node0(
    const float* __restrict__ x,
    const float* __restrict__ wq, const float* __restrict__ bq,
    const float* __restrict__ wk, const float* __restrict__ bk,
    const float* __restrict__ wv,
    float* __restrict__ Q0, float* __restrict__ K0, float* __restrict__ V0) {
    __shared__ float xs[Fdim];
    int node = blockIdx.x;
    int t = threadIdx.x;
    if (t < Fdim) xs[t] = x[(size_t)node * Fdim + t];
    __syncthreads();
    int which = t >> 6;   // 0=Q, 1=K, 2=V
    int colv = t & 63;
    const float* W = (which == 0) ? wq : ((which == 1) ? wk : wv);
    float acc = 0.f;
    #pragma unroll 4
    for (int k = 0; k < Fdim; k += 4) {
        float4 xv = *(const float4*)&xs[k];
        acc += xv.x * W[(k + 0) * 64 + colv];
        acc += xv.y * W[(k + 1) * 64 + colv];
        acc += xv.z * W[(k + 2) * 64 + colv];
        acc += xv.w * W[(k + 3) * 64 + colv];
    }
    size_t o = (size_t)node * 64 + colv;
    if (which == 0)       Q0[o] = fmaxf(acc + bq[colv], 0.f);
    else if (which == 1)  K0[o] = fmaxf(acc + bk[colv], 0.f);
    else                  V0[o] = acc;
}

// ---------------- Scatter edges into CSR order, computing att ----------------
__global__ void k_scatter(const int* __restrict__ row, const int* __restrict__ col,
                          const float* __restrict__ Q0, const float* __restrict__ K0,
                          int* __restrict__ cursor, int* __restrict__ adj_col,
                          float* __restrict__ att_csr, int E_, int Etot) {
    int t = blockIdx.x * blockDim.x + threadIdx.x;
    int e = t >> 3, h = t & 7;
    if (e >= Etot) return;
    int r, c;
    if (e < E_) { r = row[e]; c = col[e]; } else { r = e - E_; c = r; }
    const float4* q = (const float4*)&Q0[(size_t)r * 64 + h * 8];
    const float4* k = (const float4*)&K0[(size_t)c * 64 + h * 8];
    float4 q0 = q[0], q1 = q[1], k0 = k[0], k1 = k[1];
    float att = q0.x * k0.x + q0.y * k0.y + q0.z * k0.z + q0.w * k0.w
              + q1.x * k1.x + q1.y * k1.y + q1.z * k1.z + q1.w * k1.w;
    att *= 0.35355339059327373f;  // 1/sqrt(8)
    int pos = 0;
    if (h == 0) pos = atomicAdd(&cursor[r], 1);
    pos = __shfl(pos, (threadIdx.x & 63) & ~7);
    if (h == 0) adj_col[pos] = c;
    att_csr[(size_t)pos * 8 + h] = att;
}

// ---------------- Per-(node,head) segment softmax, normalized in place ----------------
__global__ void k_softmax0(const int* __restrict__ rowptr,
                           float* __restrict__ att_csr, int n) {
    int t = blockIdx.x * blockDim.x + threadIdx.x;
    if (t >= n * 8) return;
    int r = t >> 3, h = t & 7;
    int base = rowptr[r], end = rowptr[r + 1];
    float m = -INFINITY;
    for (int e = base; e < end; ++e)
        m = fmaxf(m, att_csr[(size_t)e * 8 + h]);
    float s = 0.f;
    for (int e = base; e < end; ++e) {
        float ex = __expf(att_csr[(size_t)e * 8 + h] - m);
        att_csr[(size_t)e * 8 + h] = ex;
        s += ex;
    }
    float inv = 1.f / s;
    for (int e = base; e < end; ++e)
        att_csr[(size_t)e * 8 + h] *= inv;
}

// ---------------- Layer-0 aggregation (bias+relu fused) ----------------
__global__ __launch_bounds__(256) void k_agg0(
    const int* __restrict__ rowptr, const int* __restrict__ adj_col,
    const float* __restrict__ att_csr, const float* __restrict__ V0,
    const float* __restrict__ b0, float* __restrict__ hbuf, int n) {
    int node = blockIdx.x * 4 + (threadIdx.x >> 6);
    int j = threadIdx.x & 63;
    if (node >= n) return;
    int h = j >> 3;
    int base = rowptr[node], end = rowptr[node + 1];
    float acc = 0.f;
    for (int e = base; e < end; ++e) {
        int c = adj_col[e];
        float alpha = att_csr[(size_t)e * 8 + h];
        acc += alpha * V0[(size_t)c * 64 + j];
    }
    hbuf[(size_t)node * 64 + j] = fmaxf(acc + b0[j], 0.f);
}

// ---------------- Layer 1 node transforms ----------------
__global__ __launch_bounds__(64) void k_node1(
    const float* __restrict__ hbuf,
    const float* __restrict__ wq1, const float* __restrict__ bq1,
    const float* __restrict__ wk1, const float* __restrict__ bk1,
    const float* __restrict__ wv1,
    float* __restrict__ Q1, float* __restrict__ K1, float* __restrict__ V1) {
    __shared__ float hs[64];
    int node = blockIdx.x;
    int t = threadIdx.x;
    hs[t] = hbuf[(size_t)node * 64 + t];
    __syncthreads();
    if (t < 40) {
        float acc = 0.f;
        #pragma unroll 8
        for (int k = 0; k < 64; k++) acc += hs[k] * wv1[k * 40 + t];
        V1[(size_t)node * 40 + t] = acc;
    } else if (t == 40) {
        float acc = 0.f;
        for (int k = 0; k < 64; k++) acc += hs[k] * wq1[k];
        Q1[node] = fmaxf(acc + bq1[0], 0.f);
    } else if (t == 41) {
        float acc = 0.f;
        for (int k = 0; k < 64; k++) acc += hs[k] * wk1[k];
        K1[node] = fmaxf(acc + bk1[0], 0.f);
    }
}

// ---------------- Layer-1 softmax: thread per node ----------------
__global__ void k_softmax1(const int* __restrict__ rowptr, const int* __restrict__ adj_col,
                           const float* __restrict__ Q1, const float* __restrict__ K1,
                           float* __restrict__ att1, int n) {
    int r = blockIdx.x * blockDim.x + threadIdx.x;
    if (r >= n) return;
    int base = rowptr[r], end = rowptr[r + 1];
    float qr = Q1[r];
    float m = -INFINITY;
    for (int e = base; e < end; ++e) {
        float a = qr * K1[adj_col[e]];
        att1[e] = a;
        m = fmaxf(m, a);
    }
    float s = 0.f;
    for (int e = base; e < end; ++e) {
        float ex = __expf(att1[e] - m);
        att1[e] = ex;
        s += ex;
    }
    float inv = 1.f / s;
    for (int e = base; e < end; ++e) att1[e] *= inv;
}

// ---------------- Layer-1 aggregation (+b1 fused) ----------------
__global__ __launch_bounds__(256) void k_agg1(
    const int* __restrict__ rowptr, const int* __restrict__ adj_col,
    const float* __restrict__ att1, const float* __restrict__ V1,
    const float* __restrict__ b1, float* __restrict__ out, int n) {
    int node = blockIdx.x * 4 + (threadIdx.x >> 6);
    int j = threadIdx.x & 63;
    if (node >= n || j >= 40) return;
    int base = rowptr[node], end = rowptr[node + 1];
    float acc = b1[j];
    for (int e = base; e < end; ++e) {
        int c = adj_col[e];
        acc += att1[e] * V1[(size_t)c * 40 + j];
    }
    out[(size_t)node * 40 + j] = acc;
}

extern "C" void kernel_launch(void* const* d_in, const int* in_sizes, int n_in,
                              void* d_out, int out_size, void* d_ws, size_t ws_size,
                              hipStream_t stream) {
    const float* x   = (const float*)d_in[0];
    const int*   ei  = (const int*)d_in[1];
    const float* wq0 = (const float*)d_in[2];
    const float* bq0 = (const float*)d_in[3];
    const float* wk0 = (const float*)d_in[4];
    const float* bk0 = (const float*)d_in[5];
    const float* wv0 = (const float*)d_in[6];
    const float* b0  = (const float*)d_in[7];
    const float* wq1 = (const float*)d_in[8];
    const float* bq1 = (const float*)d_in[9];
    const float* wk1 = (const float*)d_in[10];
    const float* bk1 = (const float*)d_in[11];
    const float* wv1 = (const float*)d_in[12];
    const float* b1  = (const float*)d_in[13];
    float* out = (float*)d_out;

    int n    = in_sizes[0] / Fdim;   // 50000
    int E_   = in_sizes[1] / 2;      // 800000
    int Etot = E_ + n;               // + self-loops
    const int* row = ei;
    const int* col = ei + E_;

    // Workspace layout. Region A (n*64 floats) holds Q0 during layer 0, then is
    // reused for V1/Q1/K1/att1 in layer 1 (Q0 dead after k_scatter).
    float* ws = (float*)d_ws;
    float* A       = ws; ws += (size_t)n * 64;
    float* K0      = ws; ws += (size_t)n * 64;
    float* V0      = ws; ws += (size_t)n * 64;
    float* hbuf    = ws; ws += (size_t)n * 64;
    float* att_csr = ws; ws += (size_t)Etot * 8;
    int*   adj_col = (int*)ws;
    int*   rowptr  = adj_col + Etot;
    int*   cursor  = rowptr + (n + 1);

    float* Q0   = A;
    float* V1   = A;                       // n*40
    float* Q1   = A + (size_t)n * 40;      // n
    float* K1   = A + (size_t)n * 41;      // n
    float* att1 = A + (size_t)n * 42;      // Etot floats (n*42+Etot <= n*64)

    // --- CSR build (shared by both layers) ---
    k_zero<<<(n + 255) / 256, 256, 0, stream>>>(cursor, n);
    k_hist<<<(Etot + 255) / 256, 256, 0, stream>>>(row, cursor, E_, Etot);
    k_scan<<<1, 1024, 0, stream>>>(cursor, rowptr, n);

    // --- Layer 0 ---
    k_node0<<<n, 192, 0, stream>>>(x, wq0, bq0, wk0, bk0, wv0, Q0, K0, V0);
    int t8 = Etot * 8;
    k_scatter<<<(t8 + 255) / 256, 256, 0, stream>>>(row, col, Q0, K0, cursor,
                                                    adj_col, att_csr, E_, Etot);
    k_softmax0<<<(n * 8 + 255) / 256, 256, 0, stream>>>(rowptr, att_csr, n);
    k_agg0<<<(n + 3) / 4, 256, 0, stream>>>(rowptr, adj_col, att_csr, V0, b0, hbuf, n);

    // --- Layer 1 ---
    k_node1<<<n, 64, 0, stream>>>(hbuf, wq1, bq1, wk1, bk1, wv1, Q1, K1, V1);
    k_softmax1<<<(n + 255) / 256, 256, 0, stream>>>(rowptr, adj_col, Q1, K1, att1, n);
    k_agg1<<<(n + 3) / 4, 256, 0, stream>>>(rowptr, adj_col, att1, V1, b1, out, n);
}

// Round 3
// 431.592 us; speedup vs baseline: 1.6677x; 1.2945x over previous
//
#include <hip/hip_runtime.h>
#include <math.h>

#define Fdim 128
#define BM 64

// ---------------- CSR build ----------------

__global__ void k_zero(int* deg, int n) {
    int t = blockIdx.x * blockDim.x + threadIdx.x;
    if (t < n) deg[t] = 0;
}

__global__ void k_hist(const int* __restrict__ row, int* __restrict__ deg,
                       int E_, int Etot) {
    int t = blockIdx.x * blockDim.x + threadIdx.x;
    if (t >= Etot) return;
    int r = (t < E_) ? row[t] : (t - E_);
    atomicAdd(&deg[r], 1);
}

// Phase 1: per-block (4096 elems) exclusive scan -> rowptr (local), block sums -> bsum.
__global__ __launch_bounds__(1024) void k_scan1(const int* __restrict__ cnt,
                                                int* __restrict__ local,
                                                int* __restrict__ bsum, int n) {
    __shared__ int wsum[16];
    int lane = threadIdx.x & 63, wid = threadIdx.x >> 6;
    int i0 = blockIdx.x * 4096 + threadIdx.x * 4;
    int v[4];
    #pragma unroll
    for (int j = 0; j < 4; ++j) v[j] = (i0 + j < n) ? cnt[i0 + j] : 0;
    int tsum = v[0] + v[1] + v[2] + v[3];
    int incl = tsum;
    #pragma unroll
    for (int off = 1; off < 64; off <<= 1) {
        int t = __shfl_up(incl, off);
        if (lane >= off) incl += t;
    }
    if (lane == 63) wsum[wid] = incl;
    __syncthreads();
    if (wid == 0 && lane < 16) {
        int w = wsum[lane];
        int wi = w;
        #pragma unroll
        for (int off = 1; off < 16; off <<= 1) {
            int t = __shfl_up(wi, off);
            if (lane >= off) wi += t;
        }
        wsum[lane] = wi - w;  // exclusive wave offset
    }
    __syncthreads();
    int run = (incl - tsum) + wsum[wid];   // exclusive prefix of this thread in block
    #pragma unroll
    for (int j = 0; j < 4; ++j) {
        if (i0 + j < n) local[i0 + j] = run;
        run += v[j];
    }
    if (threadIdx.x == 1023) bsum[blockIdx.x] = run;  // block total
}

// Phase 2: exclusive scan of block sums (nb <= 64), one wave.
__global__ void k_scan2(int* bsum, int nb) {
    int lane = threadIdx.x;
    int v = (lane < nb) ? bsum[lane] : 0;
    int incl = v;
    #pragma unroll
    for (int off = 1; off < 64; off <<= 1) {
        int t = __shfl_up(incl, off);
        if (lane >= off) incl += t;
    }
    if (lane < nb) bsum[lane] = incl - v;
}

// Phase 3: add block offsets in place; produce rowptr + cursor.
__global__ void k_scan3(const int* __restrict__ bsum, int* __restrict__ rowptr,
                        int* __restrict__ cursor, int n, int Etot) {
    int i = blockIdx.x * blockDim.x + threadIdx.x;
    if (i < n) {
        int v = rowptr[i] + bsum[i >> 12];
        rowptr[i] = v;
        cursor[i] = v;
    } else if (i == n) {
        rowptr[n] = Etot;
    }
}

// ---------------- Layer 0 node transforms: tiled GEMM ----------------
// [n x 128] @ ([128x64] wq | wk | wv). Block: 64 nodes, 256 threads.
// Thread (tm 0..3, tc 0..63): 16 nodes x col tc of each of the 3 matrices.
__global__ __launch_bounds__(256) void k_node0(
    const float* __restrict__ x,
    const float* __restrict__ wq, const float* __restrict__ bq,
    const float* __restrict__ wk, const float* __restrict__ bk,
    const float* __restrict__ wv,
    float* __restrict__ Q0, float* __restrict__ K0, float* __restrict__ V0, int n) {
    __shared__ float xs[BM][Fdim];   // 32 KB
    int block0 = blockIdx.x * BM;
    int t = threadIdx.x;
    {
        const float4* xsrc = (const float4*)(x + (size_t)block0 * Fdim);
        float4* xdst = (float4*)&xs[0][0];
        for (int i = t; i < BM * Fdim / 4; i += 256) {
            int rrow = i >> 5;  // i*4/128
            xdst[i] = (block0 + rrow < n) ? xsrc[i] : make_float4(0.f, 0.f, 0.f, 0.f);
        }
    }
    __syncthreads();
    int tc = t & 63;
    int tm = t >> 6;
    float accQ[16], accK[16], accV[16];
    #pragma unroll
    for (int i = 0; i < 16; ++i) { accQ[i] = 0.f; accK[i] = 0.f; accV[i] = 0.f; }
    for (int k = 0; k < Fdim; k += 4) {
        float wqv[4], wkv[4], wvv[4];
        #pragma unroll
        for (int kk = 0; kk < 4; ++kk) {
            wqv[kk] = wq[(k + kk) * 64 + tc];
            wkv[kk] = wk[(k + kk) * 64 + tc];
            wvv[kk] = wv[(k + kk) * 64 + tc];
        }
        #pragma unroll
        for (int i = 0; i < 16; ++i) {
            float4 xv = *(const float4*)&xs[tm * 16 + i][k];  // broadcast (same addr/wave)
            accQ[i] += xv.x * wqv[0] + xv.y * wqv[1] + xv.z * wqv[2] + xv.w * wqv[3];
            accK[i] += xv.x * wkv[0] + xv.y * wkv[1] + xv.z * wkv[2] + xv.w * wkv[3];
            accV[i] += xv.x * wvv[0] + xv.y * wvv[1] + xv.z * wvv[2] + xv.w * wvv[3];
        }
    }
    float bqv = bq[tc], bkv = bk[tc];
    #pragma unroll
    for (int i = 0; i < 16; ++i) {
        int node = block0 + tm * 16 + i;
        if (node < n) {
            size_t o = (size_t)node * 64 + tc;
            Q0[o] = fmaxf(accQ[i] + bqv, 0.f);
            K0[o] = fmaxf(accK[i] + bkv, 0.f);
            V0[o] = accV[i];
        }
    }
}

// ---------------- Scatter edges into CSR order, computing att ----------------
__global__ void k_scatter(const int* __restrict__ row, const int* __restrict__ col,
                          const float* __restrict__ Q0, const float* __restrict__ K0,
                          int* __restrict__ cursor, int* __restrict__ adj_col,
                          float* __restrict__ att_csr, int E_, int Etot) {
    int t = blockIdx.x * blockDim.x + threadIdx.x;
    int e = t >> 3, h = t & 7;
    if (e >= Etot) return;
    int r, c;
    if (e < E_) { r = row[e]; c = col[e]; } else { r = e - E_; c = r; }
    const float4* q = (const float4*)&Q0[(size_t)r * 64 + h * 8];
    const float4* k = (const float4*)&K0[(size_t)c * 64 + h * 8];
    float4 q0 = q[0], q1 = q[1], k0 = k[0], k1 = k[1];
    float att = q0.x * k0.x + q0.y * k0.y + q0.z * k0.z + q0.w * k0.w
              + q1.x * k1.x + q1.y * k1.y + q1.z * k1.z + q1.w * k1.w;
    att *= 0.35355339059327373f;  // 1/sqrt(8)
    int pos = 0;
    if (h == 0) pos = atomicAdd(&cursor[r], 1);
    pos = __shfl(pos, (threadIdx.x & 63) & ~7);
    if (h == 0) adj_col[pos] = c;
    att_csr[(size_t)pos * 8 + h] = att;
}

// ---------------- Per-(node,head) softmax: max pass + exp/sum pass; inv stored ----------------
__global__ void k_softmax0(const int* __restrict__ rowptr,
                           float* __restrict__ att_csr, float* __restrict__ inv0, int n) {
    int t = blockIdx.x * blockDim.x + threadIdx.x;
    if (t >= n * 8) return;
    int r = t >> 3, h = t & 7;
    int base = rowptr[r], end = rowptr[r + 1];
    float m = -INFINITY;
    for (int e = base; e < end; ++e)
        m = fmaxf(m, att_csr[(size_t)e * 8 + h]);
    float s = 0.f;
    for (int e = base; e < end; ++e) {
        float ex = __expf(att_csr[(size_t)e * 8 + h] - m);
        att_csr[(size_t)e * 8 + h] = ex;
        s += ex;
    }
    inv0[t] = 1.f / s;
}

// ---------------- Layer-0 aggregation (bias+relu fused, alpha = e * inv) ----------------
__global__ __launch_bounds__(256) void k_agg0(
    const int* __restrict__ rowptr, const int* __restrict__ adj_col,
    const float* __restrict__ att_csr, const float* __restrict__ inv0,
    const float* __restrict__ V0,
    const float* __restrict__ b0, float* __restrict__ hbuf, int n) {
    int node = blockIdx.x * 4 + (threadIdx.x >> 6);
    int j = threadIdx.x & 63;
    if (node >= n) return;
    int h = j >> 3;
    int base = rowptr[node], end = rowptr[node + 1];
    float inv = inv0[node * 8 + h];
    float acc = 0.f;
    for (int e = base; e < end; ++e) {
        int c = adj_col[e];
        acc += att_csr[(size_t)e * 8 + h] * V0[(size_t)c * 64 + j];
    }
    hbuf[(size_t)node * 64 + j] = fmaxf(acc * inv + b0[j], 0.f);
}

// ---------------- Layer 1 node transforms: 4 nodes per block ----------------
__global__ __launch_bounds__(256) void k_node1(
    const float* __restrict__ hbuf,
    const float* __restrict__ wq1, const float* __restrict__ bq1,
    const float* __restrict__ wk1, const float* __restrict__ bk1,
    const float* __restrict__ wv1,
    float* __restrict__ Q1, float* __restrict__ K1, float* __restrict__ V1, int n) {
    __shared__ float hs[4][64];
    int sub = threadIdx.x >> 6;
    int node = blockIdx.x * 4 + sub;   // n % 4 == 0 -> no partial blocks
    int t = threadIdx.x & 63;
    if (node < n) hs[sub][t] = hbuf[(size_t)node * 64 + t];
    __syncthreads();
    if (node >= n) return;
    if (t < 40) {
        float acc = 0.f;
        #pragma unroll 8
        for (int k = 0; k < 64; k++) acc += hs[sub][k] * wv1[k * 40 + t];
        V1[(size_t)node * 40 + t] = acc;
    } else if (t == 40) {
        float acc = 0.f;
        for (int k = 0; k < 64; k++) acc += hs[sub][k] * wq1[k];
        Q1[node] = fmaxf(acc + bq1[0], 0.f);
    } else if (t == 41) {
        float acc = 0.f;
        for (int k = 0; k < 64; k++) acc += hs[sub][k] * wk1[k];
        K1[node] = fmaxf(acc + bk1[0], 0.f);
    }
}

// ---------------- Layer-1 softmax: thread per node, inv stored ----------------
__global__ void k_softmax1(const int* __restrict__ rowptr, const int* __restrict__ adj_col,
                           const float* __restrict__ Q1, const float* __restrict__ K1,
                           float* __restrict__ att1, float* __restrict__ inv1, int n) {
    int r = blockIdx.x * blockDim.x + threadIdx.x;
    if (r >= n) return;
    int base = rowptr[r], end = rowptr[r + 1];
    float qr = Q1[r];
    float m = -INFINITY;
    for (int e = base; e < end; ++e) {
        float a = qr * K1[adj_col[e]];
        att1[e] = a;
        m = fmaxf(m, a);
    }
    float s = 0.f;
    for (int e = base; e < end; ++e) {
        float ex = __expf(att1[e] - m);
        att1[e] = ex;
        s += ex;
    }
    inv1[r] = 1.f / s;
}

// ---------------- Layer-1 aggregation (+b1 fused, alpha = e * inv) ----------------
__global__ __launch_bounds__(256) void k_agg1(
    const int* __restrict__ rowptr, const int* __restrict__ adj_col,
    const float* __restrict__ att1, const float* __restrict__ inv1,
    const float* __restrict__ V1,
    const float* __restrict__ b1, float* __restrict__ out, int n) {
    int node = blockIdx.x * 4 + (threadIdx.x >> 6);
    int j = threadIdx.x & 63;
    if (node >= n || j >= 40) return;
    int base = rowptr[node], end = rowptr[node + 1];
    float inv = inv1[node];
    float acc = 0.f;
    for (int e = base; e < end; ++e) {
        int c = adj_col[e];
        acc += att1[e] * V1[(size_t)c * 40 + j];
    }
    out[(size_t)node * 40 + j] = acc * inv + b1[j];
}

extern "C" void kernel_launch(void* const* d_in, const int* in_sizes, int n_in,
                              void* d_out, int out_size, void* d_ws, size_t ws_size,
                              hipStream_t stream) {
    const float* x   = (const float*)d_in[0];
    const int*   ei  = (const int*)d_in[1];
    const float* wq0 = (const float*)d_in[2];
    const float* bq0 = (const float*)d_in[3];
    const float* wk0 = (const float*)d_in[4];
    const float* bk0 = (const float*)d_in[5];
    const float* wv0 = (const float*)d_in[6];
    const float* b0  = (const float*)d_in[7];
    const float* wq1 = (const float*)d_in[8];
    const float* bq1 = (const float*)d_in[9];
    const float* wk1 = (const float*)d_in[10];
    const float* bk1 = (const float*)d_in[11];
    const float* wv1 = (const float*)d_in[12];
    const float* b1  = (const float*)d_in[13];
    float* out = (float*)d_out;

    int n    = in_sizes[0] / Fdim;   // 50000
    int E_   = in_sizes[1] / 2;      // 800000
    int Etot = E_ + n;               // + self-loops
    const int* row = ei;
    const int* col = ei + E_;

    // Workspace. Region A (n*64 floats) = Q0 during layer 0, then V1/Q1/K1/att1.
    float* ws = (float*)d_ws;
    float* A       = ws; ws += (size_t)n * 64;
    float* K0      = ws; ws += (size_t)n * 64;
    float* V0      = ws; ws += (size_t)n * 64;
    float* hbuf    = ws; ws += (size_t)n * 64;
    float* att_csr = ws; ws += (size_t)Etot * 8;
    float* inv0    = ws; ws += (size_t)n * 8;
    float* inv1    = ws; ws += n;
    int*   adj_col = (int*)ws;
    int*   rowptr  = adj_col + Etot;
    int*   cursor  = rowptr + (n + 1);
    int*   bsum    = cursor + n;

    float* Q0   = A;
    float* V1   = A;                       // n*40
    float* Q1   = A + (size_t)n * 40;      // n
    float* K1   = A + (size_t)n * 41;      // n
    float* att1 = A + (size_t)n * 42;      // Etot floats (n*42 + Etot <= n*64)

    int nb = (n + 4095) / 4096;

    // --- CSR build ---
    k_zero<<<(n + 255) / 256, 256, 0, stream>>>(cursor, n);
    k_hist<<<(Etot + 255) / 256, 256, 0, stream>>>(row, cursor, E_, Etot);
    k_scan1<<<nb, 1024, 0, stream>>>(cursor, rowptr, bsum, n);
    k_scan2<<<1, 64, 0, stream>>>(bsum, nb);
    k_scan3<<<(n + 256) / 256, 256, 0, stream>>>(bsum, rowptr, cursor, n, Etot);

    // --- Layer 0 ---
    k_node0<<<(n + BM - 1) / BM, 256, 0, stream>>>(x, wq0, bq0, wk0, bk0, wv0,
                                                   Q0, K0, V0, n);
    int t8 = Etot * 8;
    k_scatter<<<(t8 + 255) / 256, 256, 0, stream>>>(row, col, Q0, K0, cursor,
                                                    adj_col, att_csr, E_, Etot);
    k_softmax0<<<(n * 8 + 255) / 256, 256, 0, stream>>>(rowptr, att_csr, inv0, n);
    k_agg0<<<(n + 3) / 4, 256, 0, stream>>>(rowptr, adj_col, att_csr, inv0, V0, b0, hbuf, n);

    // --- Layer 1 ---
    k_node1<<<(n + 3) / 4, 256, 0, stream>>>(hbuf, wq1, bq1, wk1, bk1, wv1, Q1, K1, V1, n);
    k_softmax1<<<(n + 255) / 256, 256, 0, stream>>>(rowptr, adj_col, Q1, K1, att1, inv1, n);
    k_agg1<<<(n + 3) / 4, 256, 0, stream>>>(rowptr, adj_col, att1, inv1, V1, b1, out, n);
}

// Round 4
// 322.199 us; speedup vs baseline: 2.2339x; 1.3395x over previous
//
#include <hip/hip_runtime.h>
#include <math.h>

#define Fdim 128
#define BM 64

// ---------------- CSR build ----------------

__global__ void k_zero(int* deg, int n) {
    int t = blockIdx.x * blockDim.x + threadIdx.x;
    if (t < n) deg[t] = 0;
}

__global__ void k_hist(const int* __restrict__ row, int* __restrict__ deg,
                       int E_, int Etot) {
    int t = blockIdx.x * blockDim.x + threadIdx.x;
    if (t >= Etot) return;
    int r = (t < E_) ? row[t] : (t - E_);
    atomicAdd(&deg[r], 1);
}

// Phase 1: per-block (4096 elems) exclusive scan -> local, block sums -> bsum.
__global__ __launch_bounds__(1024) void k_scan1(const int* __restrict__ cnt,
                                                int* __restrict__ local,
                                                int* __restrict__ bsum, int n) {
    __shared__ int wsum[16];
    int lane = threadIdx.x & 63, wid = threadIdx.x >> 6;
    int i0 = blockIdx.x * 4096 + threadIdx.x * 4;
    int v[4];
    #pragma unroll
    for (int j = 0; j < 4; ++j) v[j] = (i0 + j < n) ? cnt[i0 + j] : 0;
    int tsum = v[0] + v[1] + v[2] + v[3];
    int incl = tsum;
    #pragma unroll
    for (int off = 1; off < 64; off <<= 1) {
        int t = __shfl_up(incl, off);
        if (lane >= off) incl += t;
    }
    if (lane == 63) wsum[wid] = incl;
    __syncthreads();
    if (wid == 0 && lane < 16) {
        int w = wsum[lane];
        int wi = w;
        #pragma unroll
        for (int off = 1; off < 16; off <<= 1) {
            int t = __shfl_up(wi, off);
            if (lane >= off) wi += t;
        }
        wsum[lane] = wi - w;  // exclusive wave offset
    }
    __syncthreads();
    int run = (incl - tsum) + wsum[wid];
    #pragma unroll
    for (int j = 0; j < 4; ++j) {
        if (i0 + j < n) local[i0 + j] = run;
        run += v[j];
    }
    if (threadIdx.x == 1023) bsum[blockIdx.x] = run;
}

// Phase 2: exclusive scan of block sums (nb <= 64), one wave.
__global__ void k_scan2(int* bsum, int nb) {
    int lane = threadIdx.x;
    int v = (lane < nb) ? bsum[lane] : 0;
    int incl = v;
    #pragma unroll
    for (int off = 1; off < 64; off <<= 1) {
        int t = __shfl_up(incl, off);
        if (lane >= off) incl += t;
    }
    if (lane < nb) bsum[lane] = incl - v;
}

// Phase 3: add block offsets; produce rowptr + cursor.
__global__ void k_scan3(const int* __restrict__ bsum, int* __restrict__ rowptr,
                        int* __restrict__ cursor, int n, int Etot) {
    int i = blockIdx.x * blockDim.x + threadIdx.x;
    if (i < n) {
        int v = rowptr[i] + bsum[i >> 12];
        rowptr[i] = v;
        cursor[i] = v;
    } else if (i == n) {
        rowptr[n] = Etot;
    }
}

// Scatter only the column index into CSR order.
__global__ void k_adj(const int* __restrict__ row, const int* __restrict__ col,
                      int* __restrict__ cursor, int* __restrict__ adj_col,
                      int E_, int Etot) {
    int e = blockIdx.x * blockDim.x + threadIdx.x;
    if (e >= Etot) return;
    int r, c;
    if (e < E_) { r = row[e]; c = col[e]; } else { r = e - E_; c = r; }
    int pos = atomicAdd(&cursor[r], 1);
    adj_col[pos] = c;
}

// ---------------- Layer 0 node transforms: tiled GEMM ----------------
__global__ __launch_bounds__(256) void k_node0(
    const float* __restrict__ x,
    const float* __restrict__ wq, const float* __restrict__ bq,
    const float* __restrict__ wk, const float* __restrict__ bk,
    const float* __restrict__ wv,
    float* __restrict__ Q0, float* __restrict__ K0, float* __restrict__ V0, int n) {
    __shared__ float xs[BM][Fdim];   // 32 KB
    int block0 = blockIdx.x * BM;
    int t = threadIdx.x;
    {
        const float4* xsrc = (const float4*)(x + (size_t)block0 * Fdim);
        float4* xdst = (float4*)&xs[0][0];
        for (int i = t; i < BM * Fdim / 4; i += 256) {
            int rrow = i >> 5;
            xdst[i] = (block0 + rrow < n) ? xsrc[i] : make_float4(0.f, 0.f, 0.f, 0.f);
        }
    }
    __syncthreads();
    int tc = t & 63;
    int tm = t >> 6;
    float accQ[16], accK[16], accV[16];
    #pragma unroll
    for (int i = 0; i < 16; ++i) { accQ[i] = 0.f; accK[i] = 0.f; accV[i] = 0.f; }
    for (int k = 0; k < Fdim; k += 4) {
        float wqv[4], wkv[4], wvv[4];
        #pragma unroll
        for (int kk = 0; kk < 4; ++kk) {
            wqv[kk] = wq[(k + kk) * 64 + tc];
            wkv[kk] = wk[(k + kk) * 64 + tc];
            wvv[kk] = wv[(k + kk) * 64 + tc];
        }
        #pragma unroll
        for (int i = 0; i < 16; ++i) {
            float4 xv = *(const float4*)&xs[tm * 16 + i][k];  // broadcast
            accQ[i] += xv.x * wqv[0] + xv.y * wqv[1] + xv.z * wqv[2] + xv.w * wqv[3];
            accK[i] += xv.x * wkv[0] + xv.y * wkv[1] + xv.z * wkv[2] + xv.w * wkv[3];
            accV[i] += xv.x * wvv[0] + xv.y * wvv[1] + xv.z * wvv[2] + xv.w * wvv[3];
        }
    }
    float bqv = bq[tc], bkv = bk[tc];
    #pragma unroll
    for (int i = 0; i < 16; ++i) {
        int node = block0 + tm * 16 + i;
        if (node < n) {
            size_t o = (size_t)node * 64 + tc;
            Q0[o] = fmaxf(accQ[i] + bqv, 0.f);
            K0[o] = fmaxf(accK[i] + bkv, 0.f);
            V0[o] = accV[i];
        }
    }
}

// ---------------- Layer-0 fused: att + online softmax + aggregation ----------------
// One wave per node. Lane j: head h=j>>3, dim d=j&7. Per-head dot via 8-lane
// shfl_xor reduce. Online softmax state (m,s) replicated across the 8 lanes.
__global__ __launch_bounds__(256) void k_fuse0(
    const int* __restrict__ rowptr, const int* __restrict__ adj_col,
    const float* __restrict__ Q0, const float* __restrict__ K0,
    const float* __restrict__ V0, const float* __restrict__ b0,
    float* __restrict__ hbuf, int n) {
    int node = blockIdx.x * 4 + (threadIdx.x >> 6);
    int j = threadIdx.x & 63;
    if (node >= n) return;
    float q = Q0[(size_t)node * 64 + j];
    int base = rowptr[node], end = rowptr[node + 1];
    float m = -INFINITY, s = 0.f, acc = 0.f;
    int e = base;
    for (; e + 1 < end; e += 2) {
        int c0 = adj_col[e], c1 = adj_col[e + 1];
        float k0 = K0[(size_t)c0 * 64 + j];
        float k1 = K0[(size_t)c1 * 64 + j];
        float v0 = V0[(size_t)c0 * 64 + j];
        float v1 = V0[(size_t)c1 * 64 + j];
        float p0 = q * k0, p1 = q * k1;
        #pragma unroll
        for (int off = 1; off < 8; off <<= 1) {
            p0 += __shfl_xor(p0, off);
            p1 += __shfl_xor(p1, off);
        }
        p0 *= 0.35355339059327373f;
        p1 *= 0.35355339059327373f;
        float mn = fmaxf(m, fmaxf(p0, p1));
        float scale = __expf(m - mn);          // first iter: exp(-inf)=0
        float e0 = __expf(p0 - mn);
        float e1 = __expf(p1 - mn);
        s = s * scale + e0 + e1;
        acc = acc * scale + e0 * v0 + e1 * v1;
        m = mn;
    }
    if (e < end) {
        int c0 = adj_col[e];
        float k0 = K0[(size_t)c0 * 64 + j];
        float v0 = V0[(size_t)c0 * 64 + j];
        float p0 = q * k0;
        #pragma unroll
        for (int off = 1; off < 8; off <<= 1) p0 += __shfl_xor(p0, off);
        p0 *= 0.35355339059327373f;
        float mn = fmaxf(m, p0);
        float scale = __expf(m - mn);
        float e0 = __expf(p0 - mn);
        s = s * scale + e0;
        acc = acc * scale + e0 * v0;
    }
    hbuf[(size_t)node * 64 + j] = fmaxf(acc / s + b0[j], 0.f);
}

// ---------------- Layer 1 node transforms: 4 nodes per block ----------------
__global__ __launch_bounds__(256) void k_node1(
    const float* __restrict__ hbuf,
    const float* __restrict__ wq1, const float* __restrict__ bq1,
    const float* __restrict__ wk1, const float* __restrict__ bk1,
    const float* __restrict__ wv1,
    float* __restrict__ Q1, float* __restrict__ K1, float* __restrict__ V1, int n) {
    __shared__ float hs[4][64];
    int sub = threadIdx.x >> 6;
    int node = blockIdx.x * 4 + sub;
    int t = threadIdx.x & 63;
    if (node < n) hs[sub][t] = hbuf[(size_t)node * 64 + t];
    __syncthreads();
    if (node >= n) return;
    if (t < 40) {
        float acc = 0.f;
        #pragma unroll 8
        for (int k = 0; k < 64; k++) acc += hs[sub][k] * wv1[k * 40 + t];
        V1[(size_t)node * 40 + t] = acc;
    } else if (t == 40) {
        float acc = 0.f;
        for (int k = 0; k < 64; k++) acc += hs[sub][k] * wq1[k];
        Q1[node] = fmaxf(acc + bq1[0], 0.f);
    } else if (t == 41) {
        float acc = 0.f;
        for (int k = 0; k < 64; k++) acc += hs[sub][k] * wk1[k];
        K1[node] = fmaxf(acc + bk1[0], 0.f);
    }
}

// ---------------- Layer-1 fused: att + online softmax + aggregation ----------------
// One wave per node; att is scalar per edge (H=1, A=1); lanes 0..39 carry V dims.
__global__ __launch_bounds__(256) void k_fuse1(
    const int* __restrict__ rowptr, const int* __restrict__ adj_col,
    const float* __restrict__ Q1, const float* __restrict__ K1,
    const float* __restrict__ V1, const float* __restrict__ b1,
    float* __restrict__ out, int n) {
    int node = blockIdx.x * 4 + (threadIdx.x >> 6);
    int j = threadIdx.x & 63;
    if (node >= n) return;
    float qr = Q1[node];
    int base = rowptr[node], end = rowptr[node + 1];
    float m = -INFINITY, s = 0.f, acc = 0.f;
    bool act = (j < 40);
    int e = base;
    for (; e + 1 < end; e += 2) {
        int c0 = adj_col[e], c1 = adj_col[e + 1];
        float p0 = qr * K1[c0];
        float p1 = qr * K1[c1];
        float v0 = act ? V1[(size_t)c0 * 40 + j] : 0.f;
        float v1 = act ? V1[(size_t)c1 * 40 + j] : 0.f;
        float mn = fmaxf(m, fmaxf(p0, p1));
        float scale = __expf(m - mn);
        float e0 = __expf(p0 - mn);
        float e1 = __expf(p1 - mn);
        s = s * scale + e0 + e1;
        acc = acc * scale + e0 * v0 + e1 * v1;
        m = mn;
    }
    if (e < end) {
        int c0 = adj_col[e];
        float p0 = qr * K1[c0];
        float v0 = act ? V1[(size_t)c0 * 40 + j] : 0.f;
        float mn = fmaxf(m, p0);
        float scale = __expf(m - mn);
        float e0 = __expf(p0 - mn);
        s = s * scale + e0;
        acc = acc * scale + e0 * v0;
    }
    if (act) out[(size_t)node * 40 + j] = acc / s + b1[j];
}

extern "C" void kernel_launch(void* const* d_in, const int* in_sizes, int n_in,
                              void* d_out, int out_size, void* d_ws, size_t ws_size,
                              hipStream_t stream) {
    const float* x   = (const float*)d_in[0];
    const int*   ei  = (const int*)d_in[1];
    const float* wq0 = (const float*)d_in[2];
    const float* bq0 = (const float*)d_in[3];
    const float* wk0 = (const float*)d_in[4];
    const float* bk0 = (const float*)d_in[5];
    const float* wv0 = (const float*)d_in[6];
    const float* b0  = (const float*)d_in[7];
    const float* wq1 = (const float*)d_in[8];
    const float* bq1 = (const float*)d_in[9];
    const float* wk1 = (const float*)d_in[10];
    const float* bk1 = (const float*)d_in[11];
    const float* wv1 = (const float*)d_in[12];
    const float* b1  = (const float*)d_in[13];
    float* out = (float*)d_out;

    int n    = in_sizes[0] / Fdim;   // 50000
    int E_   = in_sizes[1] / 2;      // 800000
    int Etot = E_ + n;               // + self-loops
    const int* row = ei;
    const int* col = ei + E_;

    // Workspace. Region A (n*64 floats) = Q0 during layer 0; Q0 is dead after
    // k_fuse0, so V1/Q1/K1 overlay A for layer 1.
    float* ws = (float*)d_ws;
    float* A       = ws; ws += (size_t)n * 64;
    float* K0      = ws; ws += (size_t)n * 64;
    float* V0      = ws; ws += (size_t)n * 64;
    float* hbuf    = ws; ws += (size_t)n * 64;
    int*   adj_col = (int*)ws;
    int*   rowptr  = adj_col + Etot;
    int*   cursor  = rowptr + (n + 1);
    int*   bsum    = cursor + n;

    float* Q0 = A;
    float* V1 = A;                       // n*40
    float* Q1 = A + (size_t)n * 40;      // n
    float* K1 = A + (size_t)n * 41;      // n

    int nb = (n + 4095) / 4096;

    // --- CSR build ---
    k_zero<<<(n + 255) / 256, 256, 0, stream>>>(cursor, n);
    k_hist<<<(Etot + 255) / 256, 256, 0, stream>>>(row, cursor, E_, Etot);
    k_scan1<<<nb, 1024, 0, stream>>>(cursor, rowptr, bsum, n);
    k_scan2<<<1, 64, 0, stream>>>(bsum, nb);
    k_scan3<<<(n + 256) / 256, 256, 0, stream>>>(bsum, rowptr, cursor, n, Etot);
    k_adj<<<(Etot + 255) / 256, 256, 0, stream>>>(row, col, cursor, adj_col, E_, Etot);

    // --- Layer 0 ---
    k_node0<<<(n + BM - 1) / BM, 256, 0, stream>>>(x, wq0, bq0, wk0, bk0, wv0,
                                                   Q0, K0, V0, n);
    k_fuse0<<<(n + 3) / 4, 256, 0, stream>>>(rowptr, adj_col, Q0, K0, V0, b0, hbuf, n);

    // --- Layer 1 ---
    k_node1<<<(n + 3) / 4, 256, 0, stream>>>(hbuf, wq1, bq1, wk1, bk1, wv1, Q1, K1, V1, n);
    k_fuse1<<<(n + 3) / 4, 256, 0, stream>>>(rowptr, adj_col, Q1, K1, V1, b1, out, n);
}

// Round 5
// 320.805 us; speedup vs baseline: 2.2436x; 1.0043x over previous
//
#include <hip/hip_runtime.h>
#include <math.h>

#define Fdim 128
#define BM 32

// ---------------- CSR build ----------------

__global__ void k_zero(int* deg, int n) {
    int t = blockIdx.x * blockDim.x + threadIdx.x;
    if (t < n) deg[t] = 0;
}

__global__ void k_hist(const int* __restrict__ row, int* __restrict__ deg,
                       int E_, int Etot) {
    int t = blockIdx.x * blockDim.x + threadIdx.x;
    if (t >= Etot) return;
    int r = (t < E_) ? row[t] : (t - E_);
    atomicAdd(&deg[r], 1);
}

// Phase 1: per-block (4096 elems) exclusive scan -> local, block sums -> bsum.
__global__ __launch_bounds__(1024) void k_scan1(const int* __restrict__ cnt,
                                                int* __restrict__ local,
                                                int* __restrict__ bsum, int n) {
    __shared__ int wsum[16];
    int lane = threadIdx.x & 63, wid = threadIdx.x >> 6;
    int i0 = blockIdx.x * 4096 + threadIdx.x * 4;
    int v[4];
    #pragma unroll
    for (int j = 0; j < 4; ++j) v[j] = (i0 + j < n) ? cnt[i0 + j] : 0;
    int tsum = v[0] + v[1] + v[2] + v[3];
    int incl = tsum;
    #pragma unroll
    for (int off = 1; off < 64; off <<= 1) {
        int t = __shfl_up(incl, off);
        if (lane >= off) incl += t;
    }
    if (lane == 63) wsum[wid] = incl;
    __syncthreads();
    if (wid == 0 && lane < 16) {
        int w = wsum[lane];
        int wi = w;
        #pragma unroll
        for (int off = 1; off < 16; off <<= 1) {
            int t = __shfl_up(wi, off);
            if (lane >= off) wi += t;
        }
        wsum[lane] = wi - w;  // exclusive wave offset
    }
    __syncthreads();
    int run = (incl - tsum) + wsum[wid];
    #pragma unroll
    for (int j = 0; j < 4; ++j) {
        if (i0 + j < n) local[i0 + j] = run;
        run += v[j];
    }
    if (threadIdx.x == 1023) bsum[blockIdx.x] = run;
}

// Phase 2: exclusive scan of block sums (nb <= 64), one wave.
__global__ void k_scan2(int* bsum, int nb) {
    int lane = threadIdx.x;
    int v = (lane < nb) ? bsum[lane] : 0;
    int incl = v;
    #pragma unroll
    for (int off = 1; off < 64; off <<= 1) {
        int t = __shfl_up(incl, off);
        if (lane >= off) incl += t;
    }
    if (lane < nb) bsum[lane] = incl - v;
}

// Phase 3: add block offsets; produce rowptr + cursor.
__global__ void k_scan3(const int* __restrict__ bsum, int* __restrict__ rowptr,
                        int* __restrict__ cursor, int n, int Etot) {
    int i = blockIdx.x * blockDim.x + threadIdx.x;
    if (i < n) {
        int v = rowptr[i] + bsum[i >> 12];
        rowptr[i] = v;
        cursor[i] = v;
    } else if (i == n) {
        rowptr[n] = Etot;
    }
}

// Scatter only the column index into CSR order.
__global__ void k_adj(const int* __restrict__ row, const int* __restrict__ col,
                      int* __restrict__ cursor, int* __restrict__ adj_col,
                      int E_, int Etot) {
    int e = blockIdx.x * blockDim.x + threadIdx.x;
    if (e >= Etot) return;
    int r, c;
    if (e < E_) { r = row[e]; c = col[e]; } else { r = e - E_; c = r; }
    int pos = atomicAdd(&cursor[r], 1);
    adj_col[pos] = c;
}

// ---------------- Layer 0 node transforms: tiled GEMM ----------------
// 32-node tile, 256 threads: thread (tm 0..3, tc 0..63) computes 8 nodes x col
// tc of Q, K, V. K goes to KV0[node][0..63], V to KV0[node][64..127].
__global__ __launch_bounds__(256) void k_node0(
    const float* __restrict__ x,
    const float* __restrict__ wq, const float* __restrict__ bq,
    const float* __restrict__ wk, const float* __restrict__ bk,
    const float* __restrict__ wv,
    float* __restrict__ Q0, float* __restrict__ KV0, int n) {
    __shared__ float xs[BM][Fdim];   // 16 KB
    int block0 = blockIdx.x * BM;
    int t = threadIdx.x;
    {
        const float4* xsrc = (const float4*)(x + (size_t)block0 * Fdim);
        float4* xdst = (float4*)&xs[0][0];
        #pragma unroll
        for (int i = t; i < BM * Fdim / 4; i += 256) {
            int rrow = i >> 5;   // 32 float4 per row
            xdst[i] = (block0 + rrow < n) ? xsrc[i] : make_float4(0.f, 0.f, 0.f, 0.f);
        }
    }
    __syncthreads();
    int tc = t & 63;
    int tm = t >> 6;
    float accQ[8], accK[8], accV[8];
    #pragma unroll
    for (int i = 0; i < 8; ++i) { accQ[i] = 0.f; accK[i] = 0.f; accV[i] = 0.f; }
    for (int k = 0; k < Fdim; k += 4) {
        float wqv[4], wkv[4], wvv[4];
        #pragma unroll
        for (int kk = 0; kk < 4; ++kk) {
            wqv[kk] = wq[(k + kk) * 64 + tc];
            wkv[kk] = wk[(k + kk) * 64 + tc];
            wvv[kk] = wv[(k + kk) * 64 + tc];
        }
        #pragma unroll
        for (int i = 0; i < 8; ++i) {
            float4 xv = *(const float4*)&xs[tm * 8 + i][k];  // broadcast
            accQ[i] += xv.x * wqv[0] + xv.y * wqv[1] + xv.z * wqv[2] + xv.w * wqv[3];
            accK[i] += xv.x * wkv[0] + xv.y * wkv[1] + xv.z * wkv[2] + xv.w * wkv[3];
            accV[i] += xv.x * wvv[0] + xv.y * wvv[1] + xv.z * wvv[2] + xv.w * wvv[3];
        }
    }
    float bqv = bq[tc], bkv = bk[tc];
    #pragma unroll
    for (int i = 0; i < 8; ++i) {
        int node = block0 + tm * 8 + i;
        if (node < n) {
            Q0[(size_t)node * 64 + tc]        = fmaxf(accQ[i] + bqv, 0.f);
            KV0[(size_t)node * 128 + tc]      = fmaxf(accK[i] + bkv, 0.f);
            KV0[(size_t)node * 128 + 64 + tc] = accV[i];
        }
    }
}

// ---------------- Layer-0 fused: att + online softmax + aggregation ----------------
// One wave per node. Lane j: head h=j>>3, dim d=j&7. Per-head dot via 8-lane
// shfl_xor reduce. Online softmax state (m,s) replicated across the 8 lanes.
__global__ __launch_bounds__(256) void k_fuse0(
    const int* __restrict__ rowptr, const int* __restrict__ adj_col,
    const float* __restrict__ Q0, const float* __restrict__ KV0,
    const float* __restrict__ b0,
    float* __restrict__ hbuf, int n) {
    int node = blockIdx.x * 4 + (threadIdx.x >> 6);
    int j = threadIdx.x & 63;
    if (node >= n) return;
    float q = Q0[(size_t)node * 64 + j];
    int base = rowptr[node], end = rowptr[node + 1];
    float m = -INFINITY, s = 0.f, acc = 0.f;
    int e = base;
    for (; e + 1 < end; e += 2) {
        int c0 = adj_col[e], c1 = adj_col[e + 1];
        float k0 = KV0[(size_t)c0 * 128 + j];
        float k1 = KV0[(size_t)c1 * 128 + j];
        float v0 = KV0[(size_t)c0 * 128 + 64 + j];
        float v1 = KV0[(size_t)c1 * 128 + 64 + j];
        float p0 = q * k0, p1 = q * k1;
        #pragma unroll
        for (int off = 1; off < 8; off <<= 1) {
            p0 += __shfl_xor(p0, off);
            p1 += __shfl_xor(p1, off);
        }
        p0 *= 0.35355339059327373f;
        p1 *= 0.35355339059327373f;
        float mn = fmaxf(m, fmaxf(p0, p1));
        float scale = __expf(m - mn);          // first iter: exp(-inf)=0
        float e0 = __expf(p0 - mn);
        float e1 = __expf(p1 - mn);
        s = s * scale + e0 + e1;
        acc = acc * scale + e0 * v0 + e1 * v1;
        m = mn;
    }
    if (e < end) {
        int c0 = adj_col[e];
        float k0 = KV0[(size_t)c0 * 128 + j];
        float v0 = KV0[(size_t)c0 * 128 + 64 + j];
        float p0 = q * k0;
        #pragma unroll
        for (int off = 1; off < 8; off <<= 1) p0 += __shfl_xor(p0, off);
        p0 *= 0.35355339059327373f;
        float mn = fmaxf(m, p0);
        float scale = __expf(m - mn);
        float e0 = __expf(p0 - mn);
        s = s * scale + e0;
        acc = acc * scale + e0 * v0;
    }
    hbuf[(size_t)node * 64 + j] = fmaxf(acc / s + b0[j], 0.f);
}

// ---------------- Layer 1 node transforms: 4 nodes per block ----------------
__global__ __launch_bounds__(256) void k_node1(
    const float* __restrict__ hbuf,
    const float* __restrict__ wq1, const float* __restrict__ bq1,
    const float* __restrict__ wk1, const float* __restrict__ bk1,
    const float* __restrict__ wv1,
    float* __restrict__ Q1, float* __restrict__ K1, float* __restrict__ V1, int n) {
    __shared__ float hs[4][64];
    int sub = threadIdx.x >> 6;
    int node = blockIdx.x * 4 + sub;
    int t = threadIdx.x & 63;
    if (node < n) hs[sub][t] = hbuf[(size_t)node * 64 + t];
    __syncthreads();
    if (node >= n) return;
    if (t < 40) {
        float acc = 0.f;
        #pragma unroll 8
        for (int k = 0; k < 64; k++) acc += hs[sub][k] * wv1[k * 40 + t];
        V1[(size_t)node * 40 + t] = acc;
    } else if (t == 40) {
        float acc = 0.f;
        for (int k = 0; k < 64; k++) acc += hs[sub][k] * wq1[k];
        Q1[node] = fmaxf(acc + bq1[0], 0.f);
    } else if (t == 41) {
        float acc = 0.f;
        for (int k = 0; k < 64; k++) acc += hs[sub][k] * wk1[k];
        K1[node] = fmaxf(acc + bk1[0], 0.f);
    }
}

// ---------------- Layer-1 fused: att + online softmax + aggregation ----------------
__global__ __launch_bounds__(256) void k_fuse1(
    const int* __restrict__ rowptr, const int* __restrict__ adj_col,
    const float* __restrict__ Q1, const float* __restrict__ K1,
    const float* __restrict__ V1, const float* __restrict__ b1,
    float* __restrict__ out, int n) {
    int node = blockIdx.x * 4 + (threadIdx.x >> 6);
    int j = threadIdx.x & 63;
    if (node >= n) return;
    float qr = Q1[node];
    int base = rowptr[node], end = rowptr[node + 1];
    float m = -INFINITY, s = 0.f, acc = 0.f;
    bool act = (j < 40);
    int e = base;
    for (; e + 1 < end; e += 2) {
        int c0 = adj_col[e], c1 = adj_col[e + 1];
        float p0 = qr * K1[c0];
        float p1 = qr * K1[c1];
        float v0 = act ? V1[(size_t)c0 * 40 + j] : 0.f;
        float v1 = act ? V1[(size_t)c1 * 40 + j] : 0.f;
        float mn = fmaxf(m, fmaxf(p0, p1));
        float scale = __expf(m - mn);
        float e0 = __expf(p0 - mn);
        float e1 = __expf(p1 - mn);
        s = s * scale + e0 + e1;
        acc = acc * scale + e0 * v0 + e1 * v1;
        m = mn;
    }
    if (e < end) {
        int c0 = adj_col[e];
        float p0 = qr * K1[c0];
        float v0 = act ? V1[(size_t)c0 * 40 + j] : 0.f;
        float mn = fmaxf(m, p0);
        float scale = __expf(m - mn);
        float e0 = __expf(p0 - mn);
        s = s * scale + e0;
        acc = acc * scale + e0 * v0;
    }
    if (act) out[(size_t)node * 40 + j] = acc / s + b1[j];
}

extern "C" void kernel_launch(void* const* d_in, const int* in_sizes, int n_in,
                              void* d_out, int out_size, void* d_ws, size_t ws_size,
                              hipStream_t stream) {
    const float* x   = (const float*)d_in[0];
    const int*   ei  = (const int*)d_in[1];
    const float* wq0 = (const float*)d_in[2];
    const float* bq0 = (const float*)d_in[3];
    const float* wk0 = (const float*)d_in[4];
    const float* bk0 = (const float*)d_in[5];
    const float* wv0 = (const float*)d_in[6];
    const float* b0  = (const float*)d_in[7];
    const float* wq1 = (const float*)d_in[8];
    const float* bq1 = (const float*)d_in[9];
    const float* wk1 = (const float*)d_in[10];
    const float* bk1 = (const float*)d_in[11];
    const float* wv1 = (const float*)d_in[12];
    const float* b1  = (const float*)d_in[13];
    float* out = (float*)d_out;

    int n    = in_sizes[0] / Fdim;   // 50000
    int E_   = in_sizes[1] / 2;      // 800000
    int Etot = E_ + n;               // + self-loops
    const int* row = ei;
    const int* col = ei + E_;

    // Workspace. Region A (n*64 floats) = Q0 during layer 0; Q0 dead after
    // k_fuse0, so V1/Q1/K1 overlay A for layer 1. KV0 = interleaved K|V rows.
    float* ws = (float*)d_ws;
    float* A       = ws; ws += (size_t)n * 64;
    float* KV0     = ws; ws += (size_t)n * 128;
    float* hbuf    = ws; ws += (size_t)n * 64;
    int*   adj_col = (int*)ws;
    int*   rowptr  = adj_col + Etot;
    int*   cursor  = rowptr + (n + 1);
    int*   bsum    = cursor + n;

    float* Q0 = A;
    float* V1 = A;                       // n*40
    float* Q1 = A + (size_t)n * 40;      // n
    float* K1 = A + (size_t)n * 41;      // n

    int nb = (n + 4095) / 4096;

    // --- CSR build ---
    k_zero<<<(n + 255) / 256, 256, 0, stream>>>(cursor, n);
    k_hist<<<(Etot + 255) / 256, 256, 0, stream>>>(row, cursor, E_, Etot);
    k_scan1<<<nb, 1024, 0, stream>>>(cursor, rowptr, bsum, n);
    k_scan2<<<1, 64, 0, stream>>>(bsum, nb);
    k_scan3<<<(n + 256) / 256, 256, 0, stream>>>(bsum, rowptr, cursor, n, Etot);
    k_adj<<<(Etot + 255) / 256, 256, 0, stream>>>(row, col, cursor, adj_col, E_, Etot);

    // --- Layer 0 ---
    k_node0<<<(n + BM - 1) / BM, 256, 0, stream>>>(x, wq0, bq0, wk0, bk0, wv0,
                                                   Q0, KV0, n);
    k_fuse0<<<(n + 3) / 4, 256, 0, stream>>>(rowptr, adj_col, Q0, KV0, b0, hbuf, n);

    // --- Layer 1 ---
    k_node1<<<(n + 3) / 4, 256, 0, stream>>>(hbuf, wq1, bq1, wk1, bk1, wv1, Q1, K1, V1, n);
    k_fuse1<<<(n + 3) / 4, 256, 0, stream>>>(rowptr, adj_col, Q1, K1, V1, b1, out, n);
}

// Round 6
// 307.249 us; speedup vs baseline: 2.3426x; 1.0441x over previous
//
#include <hip/hip_runtime.h>
#include <hip/hip_bf16.h>
#include <math.h>

#define Fdim 128
#define BM 32

typedef float f32x2 __attribute__((ext_vector_type(2)));

__device__ __forceinline__ f32x2 pk_fma(f32x2 a, f32x2 b, f32x2 c) {
    f32x2 d;
    asm("v_pk_fma_f32 %0, %1, %2, %3" : "=v"(d) : "v"(a), "v"(b), "v"(c));
    return d;
}

__device__ __forceinline__ unsigned short f2bf(float x) {
    __hip_bfloat16 h = __float2bfloat16(x);
    return *(unsigned short*)&h;
}
__device__ __forceinline__ float bflo(unsigned int u) {   // low 16 bits as bf16
    unsigned int b = u << 16;
    return *(float*)&b;
}
__device__ __forceinline__ float bfhi(unsigned int u) {   // high 16 bits as bf16
    unsigned int b = u & 0xffff0000u;
    return *(float*)&b;
}

// ---------------- CSR build ----------------

__global__ void k_zero(int* deg, int n) {
    int t = blockIdx.x * blockDim.x + threadIdx.x;
    if (t < n) deg[t] = 0;
}

__global__ void k_hist(const int* __restrict__ row, int* __restrict__ deg,
                       int E_, int Etot) {
    int t = blockIdx.x * blockDim.x + threadIdx.x;
    if (t >= Etot) return;
    int r = (t < E_) ? row[t] : (t - E_);
    atomicAdd(&deg[r], 1);
}

__global__ __launch_bounds__(1024) void k_scan1(const int* __restrict__ cnt,
                                                int* __restrict__ local,
                                                int* __restrict__ bsum, int n) {
    __shared__ int wsum[16];
    int lane = threadIdx.x & 63, wid = threadIdx.x >> 6;
    int i0 = blockIdx.x * 4096 + threadIdx.x * 4;
    int v[4];
    #pragma unroll
    for (int j = 0; j < 4; ++j) v[j] = (i0 + j < n) ? cnt[i0 + j] : 0;
    int tsum = v[0] + v[1] + v[2] + v[3];
    int incl = tsum;
    #pragma unroll
    for (int off = 1; off < 64; off <<= 1) {
        int t = __shfl_up(incl, off);
        if (lane >= off) incl += t;
    }
    if (lane == 63) wsum[wid] = incl;
    __syncthreads();
    if (wid == 0 && lane < 16) {
        int w = wsum[lane];
        int wi = w;
        #pragma unroll
        for (int off = 1; off < 16; off <<= 1) {
            int t = __shfl_up(wi, off);
            if (lane >= off) wi += t;
        }
        wsum[lane] = wi - w;
    }
    __syncthreads();
    int run = (incl - tsum) + wsum[wid];
    #pragma unroll
    for (int j = 0; j < 4; ++j) {
        if (i0 + j < n) local[i0 + j] = run;
        run += v[j];
    }
    if (threadIdx.x == 1023) bsum[blockIdx.x] = run;
}

__global__ void k_scan2(int* bsum, int nb) {
    int lane = threadIdx.x;
    int v = (lane < nb) ? bsum[lane] : 0;
    int incl = v;
    #pragma unroll
    for (int off = 1; off < 64; off <<= 1) {
        int t = __shfl_up(incl, off);
        if (lane >= off) incl += t;
    }
    if (lane < nb) bsum[lane] = incl - v;
}

__global__ void k_scan3(const int* __restrict__ bsum, int* __restrict__ rowptr,
                        int* __restrict__ cursor, int n, int Etot) {
    int i = blockIdx.x * blockDim.x + threadIdx.x;
    if (i < n) {
        int v = rowptr[i] + bsum[i >> 12];
        rowptr[i] = v;
        cursor[i] = v;
    } else if (i == n) {
        rowptr[n] = Etot;
    }
}

__global__ void k_adj(const int* __restrict__ row, const int* __restrict__ col,
                      int* __restrict__ cursor, int* __restrict__ adj_col,
                      int E_, int Etot) {
    int e = blockIdx.x * blockDim.x + threadIdx.x;
    if (e >= Etot) return;
    int r, c;
    if (e < E_) { r = row[e]; c = col[e]; } else { r = e - E_; c = r; }
    int pos = atomicAdd(&cursor[r], 1);
    adj_col[pos] = c;
}

// ---------------- Layer 0 node transforms: tiled GEMM, packed-f32 FMA ----------------
// 32-node tile, 256 threads: thread (tm 0..3, tc 0..63) computes 8 nodes x col tc.
// Accumulators are float2 over (k even, k odd) partial sums; v_pk_fma_f32 via asm.
// Q -> f32; K,V -> packed bf16x2 in KV0[node*64+tc] (low=K, high=V).
__global__ __launch_bounds__(256) void k_node0(
    const float* __restrict__ x,
    const float* __restrict__ wq, const float* __restrict__ bq,
    const float* __restrict__ wk, const float* __restrict__ bk,
    const float* __restrict__ wv,
    float* __restrict__ Q0, unsigned int* __restrict__ KV0, int n) {
    __shared__ float xs[BM][Fdim];   // 16 KB
    int block0 = blockIdx.x * BM;
    int t = threadIdx.x;
    {
        const float4* xsrc = (const float4*)(x + (size_t)block0 * Fdim);
        float4* xdst = (float4*)&xs[0][0];
        #pragma unroll
        for (int i = t; i < BM * Fdim / 4; i += 256) {
            int rrow = i >> 5;   // 32 float4 per row
            xdst[i] = (block0 + rrow < n) ? xsrc[i] : make_float4(0.f, 0.f, 0.f, 0.f);
        }
    }
    __syncthreads();
    int tc = t & 63;
    int tm = t >> 6;
    f32x2 aQ[8], aK[8], aV[8];
    #pragma unroll
    for (int i = 0; i < 8; ++i) {
        aQ[i] = (f32x2)(0.f); aK[i] = (f32x2)(0.f); aV[i] = (f32x2)(0.f);
    }
    for (int k = 0; k < Fdim; k += 4) {
        f32x2 wq01, wq23, wk01, wk23, wv01, wv23;
        wq01.x = wq[(k + 0) * 64 + tc]; wq01.y = wq[(k + 1) * 64 + tc];
        wq23.x = wq[(k + 2) * 64 + tc]; wq23.y = wq[(k + 3) * 64 + tc];
        wk01.x = wk[(k + 0) * 64 + tc]; wk01.y = wk[(k + 1) * 64 + tc];
        wk23.x = wk[(k + 2) * 64 + tc]; wk23.y = wk[(k + 3) * 64 + tc];
        wv01.x = wv[(k + 0) * 64 + tc]; wv01.y = wv[(k + 1) * 64 + tc];
        wv23.x = wv[(k + 2) * 64 + tc]; wv23.y = wv[(k + 3) * 64 + tc];
        #pragma unroll
        for (int i = 0; i < 8; ++i) {
            float4 xv = *(const float4*)&xs[tm * 8 + i][k];  // LDS broadcast
            f32x2 x01; x01.x = xv.x; x01.y = xv.y;
            f32x2 x23; x23.x = xv.z; x23.y = xv.w;
            aQ[i] = pk_fma(x01, wq01, aQ[i]);
            aQ[i] = pk_fma(x23, wq23, aQ[i]);
            aK[i] = pk_fma(x01, wk01, aK[i]);
            aK[i] = pk_fma(x23, wk23, aK[i]);
            aV[i] = pk_fma(x01, wv01, aV[i]);
            aV[i] = pk_fma(x23, wv23, aV[i]);
        }
    }
    float bqv = bq[tc], bkv = bk[tc];
    #pragma unroll
    for (int i = 0; i < 8; ++i) {
        int node = block0 + tm * 8 + i;
        if (node < n) {
            float q = fmaxf(aQ[i].x + aQ[i].y + bqv, 0.f);
            float kk = fmaxf(aK[i].x + aK[i].y + bkv, 0.f);
            float vv = aV[i].x + aV[i].y;
            Q0[(size_t)node * 64 + tc] = q;
            KV0[(size_t)node * 64 + tc] =
                (unsigned int)f2bf(kk) | ((unsigned int)f2bf(vv) << 16);
        }
    }
}

// ---------------- Layer-0 fused: att + online softmax + aggregation ----------------
// One wave per node. Lane j: head h=j>>3, dim d=j&7. One u32 load per edge
// yields both K (low bf16) and V (high bf16).
__global__ __launch_bounds__(256) void k_fuse0(
    const int* __restrict__ rowptr, const int* __restrict__ adj_col,
    const float* __restrict__ Q0, const unsigned int* __restrict__ KV0,
    const float* __restrict__ b0,
    float* __restrict__ hbuf, int n) {
    int node = blockIdx.x * 4 + (threadIdx.x >> 6);
    int j = threadIdx.x & 63;
    if (node >= n) return;
    float q = Q0[(size_t)node * 64 + j];
    int base = rowptr[node], end = rowptr[node + 1];
    float m = -INFINITY, s = 0.f, acc = 0.f;
    int e = base;
    for (; e + 1 < end; e += 2) {
        int c0 = adj_col[e], c1 = adj_col[e + 1];
        unsigned int kv0 = KV0[(size_t)c0 * 64 + j];
        unsigned int kv1 = KV0[(size_t)c1 * 64 + j];
        float p0 = q * bflo(kv0);
        float p1 = q * bflo(kv1);
        #pragma unroll
        for (int off = 1; off < 8; off <<= 1) {
            p0 += __shfl_xor(p0, off);
            p1 += __shfl_xor(p1, off);
        }
        p0 *= 0.35355339059327373f;
        p1 *= 0.35355339059327373f;
        float mn = fmaxf(m, fmaxf(p0, p1));
        float scale = __expf(m - mn);          // first iter: exp(-inf)=0
        float e0 = __expf(p0 - mn);
        float e1 = __expf(p1 - mn);
        s = s * scale + e0 + e1;
        acc = acc * scale + e0 * bfhi(kv0) + e1 * bfhi(kv1);
        m = mn;
    }
    if (e < end) {
        int c0 = adj_col[e];
        unsigned int kv0 = KV0[(size_t)c0 * 64 + j];
        float p0 = q * bflo(kv0);
        #pragma unroll
        for (int off = 1; off < 8; off <<= 1) p0 += __shfl_xor(p0, off);
        p0 *= 0.35355339059327373f;
        float mn = fmaxf(m, p0);
        float scale = __expf(m - mn);
        float e0 = __expf(p0 - mn);
        s = s * scale + e0;
        acc = acc * scale + e0 * bfhi(kv0);
    }
    hbuf[(size_t)node * 64 + j] = fmaxf(acc / s + b0[j], 0.f);
}

// ---------------- Layer 1 node transforms: 4 nodes per block; V1 -> bf16 ----------------
__global__ __launch_bounds__(256) void k_node1(
    const float* __restrict__ hbuf,
    const float* __restrict__ wq1, const float* __restrict__ bq1,
    const float* __restrict__ wk1, const float* __restrict__ bk1,
    const float* __restrict__ wv1,
    float* __restrict__ Q1, float* __restrict__ K1,
    unsigned short* __restrict__ V1, int n) {
    __shared__ float hs[4][64];
    int sub = threadIdx.x >> 6;
    int node = blockIdx.x * 4 + sub;
    int t = threadIdx.x & 63;
    if (node < n) hs[sub][t] = hbuf[(size_t)node * 64 + t];
    __syncthreads();
    if (node >= n) return;
    if (t < 40) {
        float acc = 0.f;
        #pragma unroll 8
        for (int k = 0; k < 64; k++) acc += hs[sub][k] * wv1[k * 40 + t];
        V1[(size_t)node * 40 + t] = f2bf(acc);
    } else if (t == 40) {
        float acc = 0.f;
        for (int k = 0; k < 64; k++) acc += hs[sub][k] * wq1[k];
        Q1[node] = fmaxf(acc + bq1[0], 0.f);
    } else if (t == 41) {
        float acc = 0.f;
        for (int k = 0; k < 64; k++) acc += hs[sub][k] * wk1[k];
        K1[node] = fmaxf(acc + bk1[0], 0.f);
    }
}

// ---------------- Layer-1 fused: att + online softmax + aggregation ----------------
__global__ __launch_bounds__(256) void k_fuse1(
    const int* __restrict__ rowptr, const int* __restrict__ adj_col,
    const float* __restrict__ Q1, const float* __restrict__ K1,
    const unsigned short* __restrict__ V1, const float* __restrict__ b1,
    float* __restrict__ out, int n) {
    int node = blockIdx.x * 4 + (threadIdx.x >> 6);
    int j = threadIdx.x & 63;
    if (node >= n) return;
    float qr = Q1[node];
    int base = rowptr[node], end = rowptr[node + 1];
    float m = -INFINITY, s = 0.f, acc = 0.f;
    bool act = (j < 40);
    int e = base;
    for (; e + 1 < end; e += 2) {
        int c0 = adj_col[e], c1 = adj_col[e + 1];
        float p0 = qr * K1[c0];
        float p1 = qr * K1[c1];
        float v0 = act ? bflo((unsigned int)V1[(size_t)c0 * 40 + j]) : 0.f;
        float v1 = act ? bflo((unsigned int)V1[(size_t)c1 * 40 + j]) : 0.f;
        float mn = fmaxf(m, fmaxf(p0, p1));
        float scale = __expf(m - mn);
        float e0 = __expf(p0 - mn);
        float e1 = __expf(p1 - mn);
        s = s * scale + e0 + e1;
        acc = acc * scale + e0 * v0 + e1 * v1;
        m = mn;
    }
    if (e < end) {
        int c0 = adj_col[e];
        float p0 = qr * K1[c0];
        float v0 = act ? bflo((unsigned int)V1[(size_t)c0 * 40 + j]) : 0.f;
        float mn = fmaxf(m, p0);
        float scale = __expf(m - mn);
        float e0 = __expf(p0 - mn);
        s = s * scale + e0;
        acc = acc * scale + e0 * v0;
    }
    if (act) out[(size_t)node * 40 + j] = acc / s + b1[j];
}

extern "C" void kernel_launch(void* const* d_in, const int* in_sizes, int n_in,
                              void* d_out, int out_size, void* d_ws, size_t ws_size,
                              hipStream_t stream) {
    const float* x   = (const float*)d_in[0];
    const int*   ei  = (const int*)d_in[1];
    const float* wq0 = (const float*)d_in[2];
    const float* bq0 = (const float*)d_in[3];
    const float* wk0 = (const float*)d_in[4];
    const float* bk0 = (const float*)d_in[5];
    const float* wv0 = (const float*)d_in[6];
    const float* b0  = (const float*)d_in[7];
    const float* wq1 = (const float*)d_in[8];
    const float* bq1 = (const float*)d_in[9];
    const float* wk1 = (const float*)d_in[10];
    const float* bk1 = (const float*)d_in[11];
    const float* wv1 = (const float*)d_in[12];
    const float* b1  = (const float*)d_in[13];
    float* out = (float*)d_out;

    int n    = in_sizes[0] / Fdim;   // 50000
    int E_   = in_sizes[1] / 2;      // 800000
    int Etot = E_ + n;               // + self-loops
    const int* row = ei;
    const int* col = ei + E_;

    // Workspace. Region A (n*64 floats) = Q0 during layer 0; after k_fuse0 it
    // is reused for V1 (bf16), Q1, K1.
    float* ws = (float*)d_ws;
    float*        A       = ws; ws += (size_t)n * 64;
    unsigned int* KV0     = (unsigned int*)ws; ws += (size_t)n * 64;  // u32 per elem
    float*        hbuf    = ws; ws += (size_t)n * 64;
    int*          adj_col = (int*)ws;
    int*          rowptr  = adj_col + Etot;
    int*          cursor  = rowptr + (n + 1);
    int*          bsum    = cursor + n;

    float*          Q0  = A;
    unsigned short* V1u = (unsigned short*)A;      // n*40 ushort = n*20 floats
    float*          Q1  = A + (size_t)n * 20;      // n
    float*          K1  = A + (size_t)n * 21;      // n

    int nb = (n + 4095) / 4096;

    // --- CSR build ---
    k_zero<<<(n + 255) / 256, 256, 0, stream>>>(cursor, n);
    k_hist<<<(Etot + 255) / 256, 256, 0, stream>>>(row, cursor, E_, Etot);
    k_scan1<<<nb, 1024, 0, stream>>>(cursor, rowptr, bsum, n);
    k_scan2<<<1, 64, 0, stream>>>(bsum, nb);
    k_scan3<<<(n + 256) / 256, 256, 0, stream>>>(bsum, rowptr, cursor, n, Etot);
    k_adj<<<(Etot + 255) / 256, 256, 0, stream>>>(row, col, cursor, adj_col, E_, Etot);

    // --- Layer 0 ---
    k_node0<<<(n + BM - 1) / BM, 256, 0, stream>>>(x, wq0, bq0, wk0, bk0, wv0,
                                                   Q0, KV0, n);
    k_fuse0<<<(n + 3) / 4, 256, 0, stream>>>(rowptr, adj_col, Q0, KV0, b0, hbuf, n);

    // --- Layer 1 ---
    k_node1<<<(n + 3) / 4, 256, 0, stream>>>(hbuf, wq1, bq1, wk1, bk1, wv1,
                                             Q1, K1, V1u, n);
    k_fuse1<<<(n + 3) / 4, 256, 0, stream>>>(rowptr, adj_col, Q1, K1, V1u, b1, out, n);
}

// Round 7
// 287.773 us; speedup vs baseline: 2.5011x; 1.0677x over previous
//
#include <hip/hip_runtime.h>
#include <hip/hip_bf16.h>
#include <math.h>

#define Fdim 128
#define BM 32

typedef float f32x2 __attribute__((ext_vector_type(2)));

__device__ __forceinline__ f32x2 pk_fma(f32x2 a, f32x2 b, f32x2 c) {
    f32x2 d;
    asm("v_pk_fma_f32 %0, %1, %2, %3" : "=v"(d) : "v"(a), "v"(b), "v"(c));
    return d;
}

__device__ __forceinline__ unsigned short f2bf(float x) {
    __hip_bfloat16 h = __float2bfloat16(x);
    return *(unsigned short*)&h;
}
__device__ __forceinline__ float bflo(unsigned int u) {   // low 16 bits as bf16
    unsigned int b = u << 16;
    return *(float*)&b;
}
__device__ __forceinline__ float bfhi(unsigned int u) {   // high 16 bits as bf16
    unsigned int b = u & 0xffff0000u;
    return *(float*)&b;
}

// ---------------- CSR build ----------------

__global__ void k_zero(int* deg, int n) {
    int t = blockIdx.x * blockDim.x + threadIdx.x;
    if (t < n) deg[t] = 0;
}

__global__ void k_hist(const int* __restrict__ row, int* __restrict__ deg,
                       int E_, int Etot) {
    int t = blockIdx.x * blockDim.x + threadIdx.x;
    if (t >= Etot) return;
    int r = (t < E_) ? row[t] : (t - E_);
    atomicAdd(&deg[r], 1);
}

__global__ __launch_bounds__(1024) void k_scan1(const int* __restrict__ cnt,
                                                int* __restrict__ local,
                                                int* __restrict__ bsum, int n) {
    __shared__ int wsum[16];
    int lane = threadIdx.x & 63, wid = threadIdx.x >> 6;
    int i0 = blockIdx.x * 4096 + threadIdx.x * 4;
    int v[4];
    #pragma unroll
    for (int j = 0; j < 4; ++j) v[j] = (i0 + j < n) ? cnt[i0 + j] : 0;
    int tsum = v[0] + v[1] + v[2] + v[3];
    int incl = tsum;
    #pragma unroll
    for (int off = 1; off < 64; off <<= 1) {
        int t = __shfl_up(incl, off);
        if (lane >= off) incl += t;
    }
    if (lane == 63) wsum[wid] = incl;
    __syncthreads();
    if (wid == 0 && lane < 16) {
        int w = wsum[lane];
        int wi = w;
        #pragma unroll
        for (int off = 1; off < 16; off <<= 1) {
            int t = __shfl_up(wi, off);
            if (lane >= off) wi += t;
        }
        wsum[lane] = wi - w;
    }
    __syncthreads();
    int run = (incl - tsum) + wsum[wid];
    #pragma unroll
    for (int j = 0; j < 4; ++j) {
        if (i0 + j < n) local[i0 + j] = run;
        run += v[j];
    }
    if (threadIdx.x == 1023) bsum[blockIdx.x] = run;
}

__global__ void k_scan2(int* bsum, int nb) {
    int lane = threadIdx.x;
    int v = (lane < nb) ? bsum[lane] : 0;
    int incl = v;
    #pragma unroll
    for (int off = 1; off < 64; off <<= 1) {
        int t = __shfl_up(incl, off);
        if (lane >= off) incl += t;
    }
    if (lane < nb) bsum[lane] = incl - v;
}

__global__ void k_scan3(const int* __restrict__ bsum, int* __restrict__ rowptr,
                        int* __restrict__ cursor, int n, int Etot) {
    int i = blockIdx.x * blockDim.x + threadIdx.x;
    if (i < n) {
        int v = rowptr[i] + bsum[i >> 12];
        rowptr[i] = v;
        cursor[i] = v;
    } else if (i == n) {
        rowptr[n] = Etot;
    }
}

__global__ void k_adj(const int* __restrict__ row, const int* __restrict__ col,
                      int* __restrict__ cursor, int* __restrict__ adj_col,
                      int E_, int Etot) {
    int e = blockIdx.x * blockDim.x + threadIdx.x;
    if (e >= Etot) return;
    int r, c;
    if (e < E_) { r = row[e]; c = col[e]; } else { r = e - E_; c = r; }
    int pos = atomicAdd(&cursor[r], 1);
    adj_col[pos] = c;
}

// ---------------- Layer 0 node transforms: tiled GEMM, packed-f32 FMA ----------------
__global__ __launch_bounds__(256) void k_node0(
    const float* __restrict__ x,
    const float* __restrict__ wq, const float* __restrict__ bq,
    const float* __restrict__ wk, const float* __restrict__ bk,
    const float* __restrict__ wv,
    float* __restrict__ Q0, unsigned int* __restrict__ KV0, int n) {
    __shared__ float xs[BM][Fdim];   // 16 KB
    int block0 = blockIdx.x * BM;
    int t = threadIdx.x;
    {
        const float4* xsrc = (const float4*)(x + (size_t)block0 * Fdim);
        float4* xdst = (float4*)&xs[0][0];
        #pragma unroll
        for (int i = t; i < BM * Fdim / 4; i += 256) {
            int rrow = i >> 5;   // 32 float4 per row
            xdst[i] = (block0 + rrow < n) ? xsrc[i] : make_float4(0.f, 0.f, 0.f, 0.f);
        }
    }
    __syncthreads();
    int tc = t & 63;
    int tm = t >> 6;
    f32x2 aQ[8], aK[8], aV[8];
    #pragma unroll
    for (int i = 0; i < 8; ++i) {
        aQ[i] = (f32x2)(0.f); aK[i] = (f32x2)(0.f); aV[i] = (f32x2)(0.f);
    }
    for (int k = 0; k < Fdim; k += 4) {
        f32x2 wq01, wq23, wk01, wk23, wv01, wv23;
        wq01.x = wq[(k + 0) * 64 + tc]; wq01.y = wq[(k + 1) * 64 + tc];
        wq23.x = wq[(k + 2) * 64 + tc]; wq23.y = wq[(k + 3) * 64 + tc];
        wk01.x = wk[(k + 0) * 64 + tc]; wk01.y = wk[(k + 1) * 64 + tc];
        wk23.x = wk[(k + 2) * 64 + tc]; wk23.y = wk[(k + 3) * 64 + tc];
        wv01.x = wv[(k + 0) * 64 + tc]; wv01.y = wv[(k + 1) * 64 + tc];
        wv23.x = wv[(k + 2) * 64 + tc]; wv23.y = wv[(k + 3) * 64 + tc];
        #pragma unroll
        for (int i = 0; i < 8; ++i) {
            float4 xv = *(const float4*)&xs[tm * 8 + i][k];  // LDS broadcast
            f32x2 x01; x01.x = xv.x; x01.y = xv.y;
            f32x2 x23; x23.x = xv.z; x23.y = xv.w;
            aQ[i] = pk_fma(x01, wq01, aQ[i]);
            aQ[i] = pk_fma(x23, wq23, aQ[i]);
            aK[i] = pk_fma(x01, wk01, aK[i]);
            aK[i] = pk_fma(x23, wk23, aK[i]);
            aV[i] = pk_fma(x01, wv01, aV[i]);
            aV[i] = pk_fma(x23, wv23, aV[i]);
        }
    }
    float bqv = bq[tc], bkv = bk[tc];
    #pragma unroll
    for (int i = 0; i < 8; ++i) {
        int node = block0 + tm * 8 + i;
        if (node < n) {
            float q = fmaxf(aQ[i].x + aQ[i].y + bqv, 0.f);
            float kk = fmaxf(aK[i].x + aK[i].y + bkv, 0.f);
            float vv = aV[i].x + aV[i].y;
            Q0[(size_t)node * 64 + tc] = q;
            KV0[(size_t)node * 64 + tc] =
                (unsigned int)f2bf(kk) | ((unsigned int)f2bf(vv) << 16);
        }
    }
}

// ---------------- Layer-0 fused: 4 independent online-softmax states ----------------
// One wave per node. Lane j: head h=j>>3, dim d=j&7. Edges round-robin into
// states 0..3; merged at the end (deg >= 1 guarantees state 0 is touched).
__global__ __launch_bounds__(256) void k_fuse0(
    const int* __restrict__ rowptr, const int* __restrict__ adj_col,
    const float* __restrict__ Q0, const unsigned int* __restrict__ KV0,
    const float* __restrict__ b0,
    float* __restrict__ hbuf, int n) {
    int node = blockIdx.x * 4 + (threadIdx.x >> 6);
    int j = threadIdx.x & 63;
    if (node >= n) return;
    float q = Q0[(size_t)node * 64 + j];
    int base = rowptr[node], end = rowptr[node + 1];
    float m0 = -INFINITY, m1 = -INFINITY, m2 = -INFINITY, m3 = -INFINITY;
    float s0 = 0.f, s1 = 0.f, s2 = 0.f, s3 = 0.f;
    float a0 = 0.f, a1 = 0.f, a2 = 0.f, a3 = 0.f;
    const float SC = 0.35355339059327373f;  // 1/sqrt(8)
    int e = base;
    for (; e + 3 < end; e += 4) {
        int c0 = adj_col[e], c1 = adj_col[e + 1], c2 = adj_col[e + 2], c3 = adj_col[e + 3];
        unsigned int kv0 = KV0[(size_t)c0 * 64 + j];
        unsigned int kv1 = KV0[(size_t)c1 * 64 + j];
        unsigned int kv2 = KV0[(size_t)c2 * 64 + j];
        unsigned int kv3 = KV0[(size_t)c3 * 64 + j];
        float p0 = q * bflo(kv0), p1 = q * bflo(kv1);
        float p2 = q * bflo(kv2), p3 = q * bflo(kv3);
        #pragma unroll
        for (int off = 1; off < 8; off <<= 1) {
            p0 += __shfl_xor(p0, off);
            p1 += __shfl_xor(p1, off);
            p2 += __shfl_xor(p2, off);
            p3 += __shfl_xor(p3, off);
        }
        p0 *= SC; p1 *= SC; p2 *= SC; p3 *= SC;
        float n0 = fmaxf(m0, p0), n1 = fmaxf(m1, p1);
        float n2 = fmaxf(m2, p2), n3 = fmaxf(m3, p3);
        float x0 = __expf(m0 - n0), x1 = __expf(m1 - n1);
        float x2 = __expf(m2 - n2), x3 = __expf(m3 - n3);
        float w0 = __expf(p0 - n0), w1 = __expf(p1 - n1);
        float w2 = __expf(p2 - n2), w3 = __expf(p3 - n3);
        s0 = s0 * x0 + w0;  a0 = a0 * x0 + w0 * bfhi(kv0);  m0 = n0;
        s1 = s1 * x1 + w1;  a1 = a1 * x1 + w1 * bfhi(kv1);  m1 = n1;
        s2 = s2 * x2 + w2;  a2 = a2 * x2 + w2 * bfhi(kv2);  m2 = n2;
        s3 = s3 * x3 + w3;  a3 = a3 * x3 + w3 * bfhi(kv3);  m3 = n3;
    }
    for (; e < end; ++e) {
        int c0 = adj_col[e];
        unsigned int kv0 = KV0[(size_t)c0 * 64 + j];
        float p0 = q * bflo(kv0);
        #pragma unroll
        for (int off = 1; off < 8; off <<= 1) p0 += __shfl_xor(p0, off);
        p0 *= SC;
        float n0 = fmaxf(m0, p0);
        float x0 = __expf(m0 - n0);
        float w0 = __expf(p0 - n0);
        s0 = s0 * x0 + w0;
        a0 = a0 * x0 + w0 * bfhi(kv0);
        m0 = n0;
    }
    // merge states (m0 finite; empty states contribute exp(-inf)=0)
    float M = fmaxf(fmaxf(m0, m1), fmaxf(m2, m3));
    float t0 = __expf(m0 - M), t1 = __expf(m1 - M);
    float t2 = __expf(m2 - M), t3 = __expf(m3 - M);
    float s = s0 * t0 + s1 * t1 + s2 * t2 + s3 * t3;
    float a = a0 * t0 + a1 * t1 + a2 * t2 + a3 * t3;
    hbuf[(size_t)node * 64 + j] = fmaxf(a / s + b0[j], 0.f);
}

// ---------------- Layer 1 node transforms: 4 nodes per block; V1 -> bf16 ----------------
__global__ __launch_bounds__(256) void k_node1(
    const float* __restrict__ hbuf,
    const float* __restrict__ wq1, const float* __restrict__ bq1,
    const float* __restrict__ wk1, const float* __restrict__ bk1,
    const float* __restrict__ wv1,
    float* __restrict__ Q1, float* __restrict__ K1,
    unsigned short* __restrict__ V1, int n) {
    __shared__ float hs[4][64];
    int sub = threadIdx.x >> 6;
    int node = blockIdx.x * 4 + sub;
    int t = threadIdx.x & 63;
    if (node < n) hs[sub][t] = hbuf[(size_t)node * 64 + t];
    __syncthreads();
    if (node >= n) return;
    if (t < 40) {
        float acc = 0.f;
        #pragma unroll 8
        for (int k = 0; k < 64; k++) acc += hs[sub][k] * wv1[k * 40 + t];
        V1[(size_t)node * 40 + t] = f2bf(acc);
    } else if (t == 40) {
        float acc = 0.f;
        for (int k = 0; k < 64; k++) acc += hs[sub][k] * wq1[k];
        Q1[node] = fmaxf(acc + bq1[0], 0.f);
    } else if (t == 41) {
        float acc = 0.f;
        for (int k = 0; k < 64; k++) acc += hs[sub][k] * wk1[k];
        K1[node] = fmaxf(acc + bk1[0], 0.f);
    }
}

// ---------------- Layer-1 fused: 4 independent online-softmax states ----------------
__global__ __launch_bounds__(256) void k_fuse1(
    const int* __restrict__ rowptr, const int* __restrict__ adj_col,
    const float* __restrict__ Q1, const float* __restrict__ K1,
    const unsigned short* __restrict__ V1, const float* __restrict__ b1,
    float* __restrict__ out, int n) {
    int node = blockIdx.x * 4 + (threadIdx.x >> 6);
    int j = threadIdx.x & 63;
    if (node >= n) return;
    float qr = Q1[node];
    int base = rowptr[node], end = rowptr[node + 1];
    bool act = (j < 40);
    float m0 = -INFINITY, m1 = -INFINITY, m2 = -INFINITY, m3 = -INFINITY;
    float s0 = 0.f, s1 = 0.f, s2 = 0.f, s3 = 0.f;
    float a0 = 0.f, a1 = 0.f, a2 = 0.f, a3 = 0.f;
    int e = base;
    for (; e + 3 < end; e += 4) {
        int c0 = adj_col[e], c1 = adj_col[e + 1], c2 = adj_col[e + 2], c3 = adj_col[e + 3];
        float p0 = qr * K1[c0], p1 = qr * K1[c1];
        float p2 = qr * K1[c2], p3 = qr * K1[c3];
        float v0 = act ? bflo((unsigned int)V1[(size_t)c0 * 40 + j]) : 0.f;
        float v1 = act ? bflo((unsigned int)V1[(size_t)c1 * 40 + j]) : 0.f;
        float v2 = act ? bflo((unsigned int)V1[(size_t)c2 * 40 + j]) : 0.f;
        float v3 = act ? bflo((unsigned int)V1[(size_t)c3 * 40 + j]) : 0.f;
        float n0 = fmaxf(m0, p0), n1 = fmaxf(m1, p1);
        float n2 = fmaxf(m2, p2), n3 = fmaxf(m3, p3);
        float x0 = __expf(m0 - n0), x1 = __expf(m1 - n1);
        float x2 = __expf(m2 - n2), x3 = __expf(m3 - n3);
        float w0 = __expf(p0 - n0), w1 = __expf(p1 - n1);
        float w2 = __expf(p2 - n2), w3 = __expf(p3 - n3);
        s0 = s0 * x0 + w0;  a0 = a0 * x0 + w0 * v0;  m0 = n0;
        s1 = s1 * x1 + w1;  a1 = a1 * x1 + w1 * v1;  m1 = n1;
        s2 = s2 * x2 + w2;  a2 = a2 * x2 + w2 * v2;  m2 = n2;
        s3 = s3 * x3 + w3;  a3 = a3 * x3 + w3 * v3;  m3 = n3;
    }
    for (; e < end; ++e) {
        int c0 = adj_col[e];
        float p0 = qr * K1[c0];
        float v0 = act ? bflo((unsigned int)V1[(size_t)c0 * 40 + j]) : 0.f;
        float n0 = fmaxf(m0, p0);
        float x0 = __expf(m0 - n0);
        float w0 = __expf(p0 - n0);
        s0 = s0 * x0 + w0;
        a0 = a0 * x0 + w0 * v0;
        m0 = n0;
    }
    float M = fmaxf(fmaxf(m0, m1), fmaxf(m2, m3));
    float t0 = __expf(m0 - M), t1 = __expf(m1 - M);
    float t2 = __expf(m2 - M), t3 = __expf(m3 - M);
    float s = s0 * t0 + s1 * t1 + s2 * t2 + s3 * t3;
    float a = a0 * t0 + a1 * t1 + a2 * t2 + a3 * t3;
    if (act) out[(size_t)node * 40 + j] = a / s + b1[j];
}

extern "C" void kernel_launch(void* const* d_in, const int* in_sizes, int n_in,
                              void* d_out, int out_size, void* d_ws, size_t ws_size,
                              hipStream_t stream) {
    const float* x   = (const float*)d_in[0];
    const int*   ei  = (const int*)d_in[1];
    const float* wq0 = (const float*)d_in[2];
    const float* bq0 = (const float*)d_in[3];
    const float* wk0 = (const float*)d_in[4];
    const float* bk0 = (const float*)d_in[5];
    const float* wv0 = (const float*)d_in[6];
    const float* b0  = (const float*)d_in[7];
    const float* wq1 = (const float*)d_in[8];
    const float* bq1 = (const float*)d_in[9];
    const float* wk1 = (const float*)d_in[10];
    const float* bk1 = (const float*)d_in[11];
    const float* wv1 = (const float*)d_in[12];
    const float* b1  = (const float*)d_in[13];
    float* out = (float*)d_out;

    int n    = in_sizes[0] / Fdim;   // 50000
    int E_   = in_sizes[1] / 2;      // 800000
    int Etot = E_ + n;               // + self-loops
    const int* row = ei;
    const int* col = ei + E_;

    // Workspace. Region A (n*64 floats) = Q0 during layer 0; after k_fuse0 it
    // is reused for V1 (bf16), Q1, K1.
    float* ws = (float*)d_ws;
    float*        A       = ws; ws += (size_t)n * 64;
    unsigned int* KV0     = (unsigned int*)ws; ws += (size_t)n * 64;  // u32 per elem
    float*        hbuf    = ws; ws += (size_t)n * 64;
    int*          adj_col = (int*)ws;
    int*          rowptr  = adj_col + Etot;
    int*          cursor  = rowptr + (n + 1);
    int*          bsum    = cursor + n;

    float*          Q0  = A;
    unsigned short* V1u = (unsigned short*)A;      // n*40 ushort = n*20 floats
    float*          Q1  = A + (size_t)n * 20;      // n
    float*          K1  = A + (size_t)n * 21;      // n

    int nb = (n + 4095) / 4096;

    // --- CSR build ---
    k_zero<<<(n + 255) / 256, 256, 0, stream>>>(cursor, n);
    k_hist<<<(Etot + 255) / 256, 256, 0, stream>>>(row, cursor, E_, Etot);
    k_scan1<<<nb, 1024, 0, stream>>>(cursor, rowptr, bsum, n);
    k_scan2<<<1, 64, 0, stream>>>(bsum, nb);
    k_scan3<<<(n + 256) / 256, 256, 0, stream>>>(bsum, rowptr, cursor, n, Etot);
    k_adj<<<(Etot + 255) / 256, 256, 0, stream>>>(row, col, cursor, adj_col, E_, Etot);

    // --- Layer 0 ---
    k_node0<<<(n + BM - 1) / BM, 256, 0, stream>>>(x, wq0, bq0, wk0, bk0, wv0,
                                                   Q0, KV0, n);
    k_fuse0<<<(n + 3) / 4, 256, 0, stream>>>(rowptr, adj_col, Q0, KV0, b0, hbuf, n);

    // --- Layer 1 ---
    k_node1<<<(n + 3) / 4, 256, 0, stream>>>(hbuf, wq1, bq1, wk1, bk1, wv1,
                                             Q1, K1, V1u, n);
    k_fuse1<<<(n + 3) / 4, 256, 0, stream>>>(rowptr, adj_col, Q1, K1, V1u, b1, out, n);
}

// Round 8
// 285.022 us; speedup vs baseline: 2.5253x; 1.0097x over previous
//
#include <hip/hip_runtime.h>
#include <hip/hip_bf16.h>
#include <math.h>

#define Fdim 128
#define BM 32
// Fixed softmax shift: p >= 0 always (relu'd Q,K); p <= ~70 worst case.
// exp(p - SHIFT) stays in [2e-9, 6e21] -- no overflow/underflow in f32.
#define SM_SHIFT 20.0f

typedef float f32x2 __attribute__((ext_vector_type(2)));

__device__ __forceinline__ f32x2 pk_fma(f32x2 a, f32x2 b, f32x2 c) {
    f32x2 d;
    asm("v_pk_fma_f32 %0, %1, %2, %3" : "=v"(d) : "v"(a), "v"(b), "v"(c));
    return d;
}

__device__ __forceinline__ unsigned short f2bf(float x) {
    __hip_bfloat16 h = __float2bfloat16(x);
    return *(unsigned short*)&h;
}
__device__ __forceinline__ float bflo(unsigned int u) {   // low 16 bits as bf16
    unsigned int b = u << 16;
    return *(float*)&b;
}
__device__ __forceinline__ float bfhi(unsigned int u) {   // high 16 bits as bf16
    unsigned int b = u & 0xffff0000u;
    return *(float*)&b;
}

// ---------------- CSR build ----------------

__global__ void k_zero(int* deg, int n) {
    int t = blockIdx.x * blockDim.x + threadIdx.x;
    if (t < n) deg[t] = 0;
}

__global__ void k_hist(const int* __restrict__ row, int* __restrict__ deg,
                       int E_, int Etot) {
    int t = blockIdx.x * blockDim.x + threadIdx.x;
    if (t >= Etot) return;
    int r = (t < E_) ? row[t] : (t - E_);
    atomicAdd(&deg[r], 1);
}

__global__ __launch_bounds__(1024) void k_scan1(const int* __restrict__ cnt,
                                                int* __restrict__ local,
                                                int* __restrict__ bsum, int n) {
    __shared__ int wsum[16];
    int lane = threadIdx.x & 63, wid = threadIdx.x >> 6;
    int i0 = blockIdx.x * 4096 + threadIdx.x * 4;
    int v[4];
    #pragma unroll
    for (int j = 0; j < 4; ++j) v[j] = (i0 + j < n) ? cnt[i0 + j] : 0;
    int tsum = v[0] + v[1] + v[2] + v[3];
    int incl = tsum;
    #pragma unroll
    for (int off = 1; off < 64; off <<= 1) {
        int t = __shfl_up(incl, off);
        if (lane >= off) incl += t;
    }
    if (lane == 63) wsum[wid] = incl;
    __syncthreads();
    if (wid == 0 && lane < 16) {
        int w = wsum[lane];
        int wi = w;
        #pragma unroll
        for (int off = 1; off < 16; off <<= 1) {
            int t = __shfl_up(wi, off);
            if (lane >= off) wi += t;
        }
        wsum[lane] = wi - w;
    }
    __syncthreads();
    int run = (incl - tsum) + wsum[wid];
    #pragma unroll
    for (int j = 0; j < 4; ++j) {
        if (i0 + j < n) local[i0 + j] = run;
        run += v[j];
    }
    if (threadIdx.x == 1023) bsum[blockIdx.x] = run;
}

__global__ void k_scan2(int* bsum, int nb) {
    int lane = threadIdx.x;
    int v = (lane < nb) ? bsum[lane] : 0;
    int incl = v;
    #pragma unroll
    for (int off = 1; off < 64; off <<= 1) {
        int t = __shfl_up(incl, off);
        if (lane >= off) incl += t;
    }
    if (lane < nb) bsum[lane] = incl - v;
}

__global__ void k_scan3(const int* __restrict__ bsum, int* __restrict__ rowptr,
                        int* __restrict__ cursor, int n, int Etot) {
    int i = blockIdx.x * blockDim.x + threadIdx.x;
    if (i < n) {
        int v = rowptr[i] + bsum[i >> 12];
        rowptr[i] = v;
        cursor[i] = v;
    } else if (i == n) {
        rowptr[n] = Etot;
    }
}

__global__ void k_adj(const int* __restrict__ row, const int* __restrict__ col,
                      int* __restrict__ cursor, int* __restrict__ adj_col,
                      int E_, int Etot) {
    int e = blockIdx.x * blockDim.x + threadIdx.x;
    if (e >= Etot) return;
    int r, c;
    if (e < E_) { r = row[e]; c = col[e]; } else { r = e - E_; c = r; }
    int pos = atomicAdd(&cursor[r], 1);
    adj_col[pos] = c;
}

// ---------------- Layer 0 node transforms: tiled GEMM, packed-f32 FMA ----------------
__global__ __launch_bounds__(256) void k_node0(
    const float* __restrict__ x,
    const float* __restrict__ wq, const float* __restrict__ bq,
    const float* __restrict__ wk, const float* __restrict__ bk,
    const float* __restrict__ wv,
    float* __restrict__ Q0, unsigned int* __restrict__ KV0, int n) {
    __shared__ float xs[BM][Fdim];   // 16 KB
    int block0 = blockIdx.x * BM;
    int t = threadIdx.x;
    {
        const float4* xsrc = (const float4*)(x + (size_t)block0 * Fdim);
        float4* xdst = (float4*)&xs[0][0];
        #pragma unroll
        for (int i = t; i < BM * Fdim / 4; i += 256) {
            int rrow = i >> 5;   // 32 float4 per row
            xdst[i] = (block0 + rrow < n) ? xsrc[i] : make_float4(0.f, 0.f, 0.f, 0.f);
        }
    }
    __syncthreads();
    int tc = t & 63;
    int tm = t >> 6;
    f32x2 aQ[8], aK[8], aV[8];
    #pragma unroll
    for (int i = 0; i < 8; ++i) {
        aQ[i] = (f32x2)(0.f); aK[i] = (f32x2)(0.f); aV[i] = (f32x2)(0.f);
    }
    for (int k = 0; k < Fdim; k += 4) {
        f32x2 wq01, wq23, wk01, wk23, wv01, wv23;
        wq01.x = wq[(k + 0) * 64 + tc]; wq01.y = wq[(k + 1) * 64 + tc];
        wq23.x = wq[(k + 2) * 64 + tc]; wq23.y = wq[(k + 3) * 64 + tc];
        wk01.x = wk[(k + 0) * 64 + tc]; wk01.y = wk[(k + 1) * 64 + tc];
        wk23.x = wk[(k + 2) * 64 + tc]; wk23.y = wk[(k + 3) * 64 + tc];
        wv01.x = wv[(k + 0) * 64 + tc]; wv01.y = wv[(k + 1) * 64 + tc];
        wv23.x = wv[(k + 2) * 64 + tc]; wv23.y = wv[(k + 3) * 64 + tc];
        #pragma unroll
        for (int i = 0; i < 8; ++i) {
            float4 xv = *(const float4*)&xs[tm * 8 + i][k];  // LDS broadcast
            f32x2 x01; x01.x = xv.x; x01.y = xv.y;
            f32x2 x23; x23.x = xv.z; x23.y = xv.w;
            aQ[i] = pk_fma(x01, wq01, aQ[i]);
            aQ[i] = pk_fma(x23, wq23, aQ[i]);
            aK[i] = pk_fma(x01, wk01, aK[i]);
            aK[i] = pk_fma(x23, wk23, aK[i]);
            aV[i] = pk_fma(x01, wv01, aV[i]);
            aV[i] = pk_fma(x23, wv23, aV[i]);
        }
    }
    float bqv = bq[tc], bkv = bk[tc];
    #pragma unroll
    for (int i = 0; i < 8; ++i) {
        int node = block0 + tm * 8 + i;
        if (node < n) {
            float q = fmaxf(aQ[i].x + aQ[i].y + bqv, 0.f);
            float kk = fmaxf(aK[i].x + aK[i].y + bkv, 0.f);
            float vv = aV[i].x + aV[i].y;
            Q0[(size_t)node * 64 + tc] = q;
            KV0[(size_t)node * 64 + tc] =
                (unsigned int)f2bf(kk) | ((unsigned int)f2bf(vv) << 16);
        }
    }
}

// ---------------- Layer-0 fused: fixed-shift softmax + aggregation ----------------
// One wave per node. Lane j: head h=j>>3, dim d=j&7. No running max: p >= 0,
// bounded; w = exp(p - SM_SHIFT). Pure associative accumulation, 4-deep unroll.
__global__ __launch_bounds__(256) void k_fuse0(
    const int* __restrict__ rowptr, const int* __restrict__ adj_col,
    const float* __restrict__ Q0, const unsigned int* __restrict__ KV0,
    const float* __restrict__ b0,
    float* __restrict__ hbuf, int n) {
    int node = blockIdx.x * 4 + (threadIdx.x >> 6);
    int j = threadIdx.x & 63;
    if (node >= n) return;
    float q = Q0[(size_t)node * 64 + j] * 0.35355339059327373f;  // fold 1/sqrt(8)
    int base = rowptr[node], end = rowptr[node + 1];
    float s0 = 0.f, s1 = 0.f, s2 = 0.f, s3 = 0.f;
    float a0 = 0.f, a1 = 0.f, a2 = 0.f, a3 = 0.f;
    int e = base;
    for (; e + 3 < end; e += 4) {
        int c0 = adj_col[e], c1 = adj_col[e + 1], c2 = adj_col[e + 2], c3 = adj_col[e + 3];
        unsigned int kv0 = KV0[(size_t)c0 * 64 + j];
        unsigned int kv1 = KV0[(size_t)c1 * 64 + j];
        unsigned int kv2 = KV0[(size_t)c2 * 64 + j];
        unsigned int kv3 = KV0[(size_t)c3 * 64 + j];
        float p0 = q * bflo(kv0), p1 = q * bflo(kv1);
        float p2 = q * bflo(kv2), p3 = q * bflo(kv3);
        #pragma unroll
        for (int off = 1; off < 8; off <<= 1) {
            p0 += __shfl_xor(p0, off);
            p1 += __shfl_xor(p1, off);
            p2 += __shfl_xor(p2, off);
            p3 += __shfl_xor(p3, off);
        }
        float w0 = __expf(p0 - SM_SHIFT);
        float w1 = __expf(p1 - SM_SHIFT);
        float w2 = __expf(p2 - SM_SHIFT);
        float w3 = __expf(p3 - SM_SHIFT);
        s0 += w0;  a0 += w0 * bfhi(kv0);
        s1 += w1;  a1 += w1 * bfhi(kv1);
        s2 += w2;  a2 += w2 * bfhi(kv2);
        s3 += w3;  a3 += w3 * bfhi(kv3);
    }
    for (; e < end; ++e) {
        int c0 = adj_col[e];
        unsigned int kv0 = KV0[(size_t)c0 * 64 + j];
        float p0 = q * bflo(kv0);
        #pragma unroll
        for (int off = 1; off < 8; off <<= 1) p0 += __shfl_xor(p0, off);
        float w0 = __expf(p0 - SM_SHIFT);
        s0 += w0;
        a0 += w0 * bfhi(kv0);
    }
    float s = (s0 + s1) + (s2 + s3);
    float a = (a0 + a1) + (a2 + a3);
    hbuf[(size_t)node * 64 + j] = fmaxf(a / s + b0[j], 0.f);
}

// ---------------- Layer 1 node transforms: 4 nodes per block; V1 -> bf16 ----------------
__global__ __launch_bounds__(256) void k_node1(
    const float* __restrict__ hbuf,
    const float* __restrict__ wq1, const float* __restrict__ bq1,
    const float* __restrict__ wk1, const float* __restrict__ bk1,
    const float* __restrict__ wv1,
    float* __restrict__ Q1, float* __restrict__ K1,
    unsigned short* __restrict__ V1, int n) {
    __shared__ float hs[4][64];
    int sub = threadIdx.x >> 6;
    int node = blockIdx.x * 4 + sub;
    int t = threadIdx.x & 63;
    if (node < n) hs[sub][t] = hbuf[(size_t)node * 64 + t];
    __syncthreads();
    if (node >= n) return;
    if (t < 40) {
        float acc = 0.f;
        #pragma unroll 8
        for (int k = 0; k < 64; k++) acc += hs[sub][k] * wv1[k * 40 + t];
        V1[(size_t)node * 40 + t] = f2bf(acc);
    } else if (t == 40) {
        float acc = 0.f;
        for (int k = 0; k < 64; k++) acc += hs[sub][k] * wq1[k];
        Q1[node] = fmaxf(acc + bq1[0], 0.f);
    } else if (t == 41) {
        float acc = 0.f;
        for (int k = 0; k < 64; k++) acc += hs[sub][k] * wk1[k];
        K1[node] = fmaxf(acc + bk1[0], 0.f);
    }
}

// ---------------- Layer-1 fused: fixed-shift softmax + aggregation ----------------
// One wave per node; p = Q1[node]*K1[c] is scalar (>=0, bounded). 8-deep unroll.
__global__ __launch_bounds__(256) void k_fuse1(
    const int* __restrict__ rowptr, const int* __restrict__ adj_col,
    const float* __restrict__ Q1, const float* __restrict__ K1,
    const unsigned short* __restrict__ V1, const float* __restrict__ b1,
    float* __restrict__ out, int n) {
    int node = blockIdx.x * 4 + (threadIdx.x >> 6);
    int j = threadIdx.x & 63;
    if (node >= n) return;
    float qr = Q1[node];
    int base = rowptr[node], end = rowptr[node + 1];
    bool act = (j < 40);
    float s0 = 0.f, s1 = 0.f, s2 = 0.f, s3 = 0.f;
    float a0 = 0.f, a1 = 0.f, a2 = 0.f, a3 = 0.f;
    int e = base;
    for (; e + 7 < end; e += 8) {
        int c0 = adj_col[e],     c1 = adj_col[e + 1], c2 = adj_col[e + 2], c3 = adj_col[e + 3];
        int c4 = adj_col[e + 4], c5 = adj_col[e + 5], c6 = adj_col[e + 6], c7 = adj_col[e + 7];
        float w0 = __expf(qr * K1[c0] - SM_SHIFT);
        float w1 = __expf(qr * K1[c1] - SM_SHIFT);
        float w2 = __expf(qr * K1[c2] - SM_SHIFT);
        float w3 = __expf(qr * K1[c3] - SM_SHIFT);
        float w4 = __expf(qr * K1[c4] - SM_SHIFT);
        float w5 = __expf(qr * K1[c5] - SM_SHIFT);
        float w6 = __expf(qr * K1[c6] - SM_SHIFT);
        float w7 = __expf(qr * K1[c7] - SM_SHIFT);
        float v0 = act ? bflo((unsigned int)V1[(size_t)c0 * 40 + j]) : 0.f;
        float v1 = act ? bflo((unsigned int)V1[(size_t)c1 * 40 + j]) : 0.f;
        float v2 = act ? bflo((unsigned int)V1[(size_t)c2 * 40 + j]) : 0.f;
        float v3 = act ? bflo((unsigned int)V1[(size_t)c3 * 40 + j]) : 0.f;
        float v4 = act ? bflo((unsigned int)V1[(size_t)c4 * 40 + j]) : 0.f;
        float v5 = act ? bflo((unsigned int)V1[(size_t)c5 * 40 + j]) : 0.f;
        float v6 = act ? bflo((unsigned int)V1[(size_t)c6 * 40 + j]) : 0.f;
        float v7 = act ? bflo((unsigned int)V1[(size_t)c7 * 40 + j]) : 0.f;
        s0 += w0 + w4;  a0 += w0 * v0 + w4 * v4;
        s1 += w1 + w5;  a1 += w1 * v1 + w5 * v5;
        s2 += w2 + w6;  a2 += w2 * v2 + w6 * v6;
        s3 += w3 + w7;  a3 += w3 * v3 + w7 * v7;
    }
    for (; e < end; ++e) {
        int c0 = adj_col[e];
        float w0 = __expf(qr * K1[c0] - SM_SHIFT);
        float v0 = act ? bflo((unsigned int)V1[(size_t)c0 * 40 + j]) : 0.f;
        s0 += w0;
        a0 += w0 * v0;
    }
    float s = (s0 + s1) + (s2 + s3);
    float a = (a0 + a1) + (a2 + a3);
    if (act) out[(size_t)node * 40 + j] = a / s + b1[j];
}

extern "C" void kernel_launch(void* const* d_in, const int* in_sizes, int n_in,
                              void* d_out, int out_size, void* d_ws, size_t ws_size,
                              hipStream_t stream) {
    const float* x   = (const float*)d_in[0];
    const int*   ei  = (const int*)d_in[1];
    const float* wq0 = (const float*)d_in[2];
    const float* bq0 = (const float*)d_in[3];
    const float* wk0 = (const float*)d_in[4];
    const float* bk0 = (const float*)d_in[5];
    const float* wv0 = (const float*)d_in[6];
    const float* b0  = (const float*)d_in[7];
    const float* wq1 = (const float*)d_in[8];
    const float* bq1 = (const float*)d_in[9];
    const float* wk1 = (const float*)d_in[10];
    const float* bk1 = (const float*)d_in[11];
    const float* wv1 = (const float*)d_in[12];
    const float* b1  = (const float*)d_in[13];
    float* out = (float*)d_out;

    int n    = in_sizes[0] / Fdim;   // 50000
    int E_   = in_sizes[1] / 2;      // 800000
    int Etot = E_ + n;               // + self-loops
    const int* row = ei;
    const int* col = ei + E_;

    // Workspace. Region A (n*64 floats) = Q0 during layer 0; after k_fuse0 it
    // is reused for V1 (bf16), Q1, K1.
    float* ws = (float*)d_ws;
    float*        A       = ws; ws += (size_t)n * 64;
    unsigned int* KV0     = (unsigned int*)ws; ws += (size_t)n * 64;  // u32 per elem
    float*        hbuf    = ws; ws += (size_t)n * 64;
    int*          adj_col = (int*)ws;
    int*          rowptr  = adj_col + Etot;
    int*          cursor  = rowptr + (n + 1);
    int*          bsum    = cursor + n;

    float*          Q0  = A;
    unsigned short* V1u = (unsigned short*)A;      // n*40 ushort = n*20 floats
    float*          Q1  = A + (size_t)n * 20;      // n
    float*          K1  = A + (size_t)n * 21;      // n

    int nb = (n + 4095) / 4096;

    // --- CSR build ---
    k_zero<<<(n + 255) / 256, 256, 0, stream>>>(cursor, n);
    k_hist<<<(Etot + 255) / 256, 256, 0, stream>>>(row, cursor, E_, Etot);
    k_scan1<<<nb, 1024, 0, stream>>>(cursor, rowptr, bsum, n);
    k_scan2<<<1, 64, 0, stream>>>(bsum, nb);
    k_scan3<<<(n + 256) / 256, 256, 0, stream>>>(bsum, rowptr, cursor, n, Etot);
    k_adj<<<(Etot + 255) / 256, 256, 0, stream>>>(row, col, cursor, adj_col, E_, Etot);

    // --- Layer 0 ---
    k_node0<<<(n + BM - 1) / BM, 256, 0, stream>>>(x, wq0, bq0, wk0, bk0, wv0,
                                                   Q0, KV0, n);
    k_fuse0<<<(n + 3) / 4, 256, 0, stream>>>(rowptr, adj_col, Q0, KV0, b0, hbuf, n);

    // --- Layer 1 ---
    k_node1<<<(n + 3) / 4, 256, 0, stream>>>(hbuf, wq1, bq1, wk1, bk1, wv1,
                                             Q1, K1, V1u, n);
    k_fuse1<<<(n + 3) / 4, 256, 0, stream>>>(rowptr, adj_col, Q1, K1, V1u, b1, out, n);
}